// Round 1
// baseline (2780.354 us; speedup 1.0000x reference)
//
#include <hip/hip_runtime.h>
#include <hip/hip_bf16.h>
#include <cstdint>

#define T_TOK   4096
#define H_DIM   1024
#define NHEAD   16
#define NKVH    4
#define HDIM    64
#define NEXP    8
#define FF      2048
#define MAXROWS 8704
#define MAXTILES 136

// ---------------- RMSNorm: one block per token ----------------
__global__ __launch_bounds__(256) void rmsnorm_kernel(
    const float* __restrict__ x, const float* __restrict__ w, float* __restrict__ out) {
  int t = blockIdx.x, tid = threadIdx.x;
  const float4 xv = *(const float4*)(x + (size_t)t * H_DIM + tid * 4);
  float ss = xv.x * xv.x + xv.y * xv.y + xv.z * xv.z + xv.w * xv.w;
#pragma unroll
  for (int off = 32; off > 0; off >>= 1) ss += __shfl_down(ss, off);
  __shared__ float red[4];
  if ((tid & 63) == 0) red[tid >> 6] = ss;
  __syncthreads();
  float tot = red[0] + red[1] + red[2] + red[3];
  float rs = rsqrtf(tot * (1.0f / 1024.0f) + 1e-6f);
  const float4 wv = *(const float4*)(w + tid * 4);
  float4 o;
  o.x = xv.x * rs * wv.x; o.y = xv.y * rs * wv.y;
  o.z = xv.z * rs * wv.z; o.w = xv.w * rs * wv.w;
  *(float4*)(out + (size_t)t * H_DIM + tid * 4) = o;
}

// ---------------- Generic fp32 tiled GEMM: C = A@B (+Res) ----------------
// 64x64 tile, BK=16, 256 threads, 4x4 micro-tile per thread.
template <bool RES>
__global__ __launch_bounds__(256) void gemm_f32(
    const float* __restrict__ A, const float* __restrict__ B,
    const float* __restrict__ Res, float* __restrict__ C,
    int M, int N, int K) {
  __shared__ float As[16][68];  // As[k][m], pad->stride 68 (16B aligned, conflict-free)
  __shared__ float Bs[16][64];  // Bs[k][n]
  const int tid = threadIdx.x;
  const int row0 = blockIdx.y * 64, col0 = blockIdx.x * 64;
  const int tx = tid & 15, ty = tid >> 4;
  const int aM = tid >> 2, aK = (tid & 3) * 4;
  const int bK = tid >> 4, bN = (tid & 15) * 4;
  float acc[4][4] = {};
  for (int k0 = 0; k0 < K; k0 += 16) {
    float4 av = *(const float4*)(A + (size_t)(row0 + aM) * K + k0 + aK);
    As[aK + 0][aM] = av.x; As[aK + 1][aM] = av.y;
    As[aK + 2][aM] = av.z; As[aK + 3][aM] = av.w;
    *(float4*)(&Bs[bK][bN]) = *(const float4*)(B + (size_t)(k0 + bK) * N + col0 + bN);
    __syncthreads();
#pragma unroll
    for (int kk = 0; kk < 16; ++kk) {
      float4 a = *(const float4*)(&As[kk][ty * 4]);
      float4 b = *(const float4*)(&Bs[kk][tx * 4]);
      float ar[4] = {a.x, a.y, a.z, a.w};
      float br[4] = {b.x, b.y, b.z, b.w};
#pragma unroll
      for (int i = 0; i < 4; ++i)
#pragma unroll
        for (int j = 0; j < 4; ++j) acc[i][j] += ar[i] * br[j];
    }
    __syncthreads();
  }
#pragma unroll
  for (int i = 0; i < 4; ++i) {
    size_t r = (size_t)(row0 + ty * 4 + i) * N + col0 + tx * 4;
    float4 o;
    o.x = acc[i][0]; o.y = acc[i][1]; o.z = acc[i][2]; o.w = acc[i][3];
    if (RES) {
      float4 rv = *(const float4*)(Res + r);
      o.x += rv.x; o.y += rv.y; o.z += rv.z; o.w += rv.w;
    }
    *(float4*)(C + r) = o;
  }
}

// ---------------- Flash attention, causal, GQA (rep=4) ----------------
// grid (S/64, NH, B), 256 threads. Thread owns row r=tid>>2, col-chunk c4=tid&3 (16 cols/dims).
__global__ __launch_bounds__(256) void attn_kernel(
    const float* __restrict__ q, const float* __restrict__ k,
    const float* __restrict__ v, float* __restrict__ o) {
  const int qt = blockIdx.x, h = blockIdx.y, b = blockIdx.z;
  const int kvh = h >> 2;
  __shared__ float Qs[64][68];
  __shared__ float KPs[64][68];  // K tile, reused as P tile (keeps LDS <= 64KB)
  __shared__ float Vs[64][64];
  const int tid = threadIdx.x;
  const int r = tid >> 2, c4 = tid & 3;
#pragma unroll
  for (int l = 0; l < 4; ++l) {
    int idx = tid + l * 256, m = idx >> 4, d4 = idx & 15;
    *(float4*)(&Qs[m][d4 * 4]) =
        *(const float4*)(q + (size_t)(b * 1024 + qt * 64 + m) * 1024 + h * 64 + d4 * 4);
  }
  float m_i = -3.0e38f, l_i = 0.0f;
  float O[16];
#pragma unroll
  for (int j = 0; j < 16; ++j) O[j] = 0.0f;
  const int qi = qt * 64 + r;

  for (int kt = 0; kt <= qt; ++kt) {
#pragma unroll
    for (int l = 0; l < 4; ++l) {
      int idx = tid + l * 256, m = idx >> 4, d4 = idx & 15;
      size_t base = (size_t)(b * 1024 + kt * 64 + m) * 256 + kvh * 64 + d4 * 4;
      *(float4*)(&KPs[m][d4 * 4]) = *(const float4*)(k + base);
      *(float4*)(&Vs[m][d4 * 4]) = *(const float4*)(v + base);
    }
    __syncthreads();
    // S = Q K^T for 16 cols
    float s[16];
#pragma unroll
    for (int j = 0; j < 16; ++j) s[j] = 0.0f;
#pragma unroll 4
    for (int d4 = 0; d4 < 16; ++d4) {
      float4 qv = *(const float4*)(&Qs[r][d4 * 4]);
#pragma unroll
      for (int j = 0; j < 16; ++j) {
        float4 kv = *(const float4*)(&KPs[c4 * 16 + j][d4 * 4]);
        s[j] += qv.x * kv.x + qv.y * kv.y + qv.z * kv.z + qv.w * kv.w;
      }
    }
    const int kbase = kt * 64 + c4 * 16;
#pragma unroll
    for (int j = 0; j < 16; ++j) {
      s[j] *= 0.125f;
      if (kbase + j > qi) s[j] = -3.0e38f;
    }
    float mx = s[0];
#pragma unroll
    for (int j = 1; j < 16; ++j) mx = fmaxf(mx, s[j]);
    mx = fmaxf(mx, __shfl_xor(mx, 1));
    mx = fmaxf(mx, __shfl_xor(mx, 2));
    float m_new = fmaxf(m_i, mx);
    float p[16], rs = 0.0f;
#pragma unroll
    for (int j = 0; j < 16; ++j) { p[j] = __expf(s[j] - m_new); rs += p[j]; }
    rs += __shfl_xor(rs, 1);
    rs += __shfl_xor(rs, 2);
    float alpha = __expf(m_i - m_new);
    l_i = l_i * alpha + rs;
    m_i = m_new;
#pragma unroll
    for (int j = 0; j < 16; ++j) O[j] *= alpha;
    __syncthreads();  // done reading KPs as K
#pragma unroll
    for (int j4 = 0; j4 < 4; ++j4) {
      float4 pv;
      pv.x = p[j4 * 4 + 0]; pv.y = p[j4 * 4 + 1];
      pv.z = p[j4 * 4 + 2]; pv.w = p[j4 * 4 + 3];
      *(float4*)(&KPs[r][c4 * 16 + j4 * 4]) = pv;
    }
    __syncthreads();
    // O += P @ V  (thread's dims = c4*16 .. +15)
#pragma unroll 8
    for (int kk = 0; kk < 64; ++kk) {
      float pw = KPs[r][kk];
      float4 v0 = *(const float4*)(&Vs[kk][c4 * 16 + 0]);
      float4 v1 = *(const float4*)(&Vs[kk][c4 * 16 + 4]);
      float4 v2 = *(const float4*)(&Vs[kk][c4 * 16 + 8]);
      float4 v3 = *(const float4*)(&Vs[kk][c4 * 16 + 12]);
      O[0] += pw * v0.x; O[1] += pw * v0.y; O[2] += pw * v0.z; O[3] += pw * v0.w;
      O[4] += pw * v1.x; O[5] += pw * v1.y; O[6] += pw * v1.z; O[7] += pw * v1.w;
      O[8] += pw * v2.x; O[9] += pw * v2.y; O[10] += pw * v2.z; O[11] += pw * v2.w;
      O[12] += pw * v3.x; O[13] += pw * v3.y; O[14] += pw * v3.z; O[15] += pw * v3.w;
    }
    __syncthreads();
  }
  float inv = 1.0f / l_i;
  size_t ob = (size_t)(b * 1024 + qt * 64 + r) * 1024 + h * 64 + c4 * 16;
#pragma unroll
  for (int j4 = 0; j4 < 4; ++j4) {
    float4 ov;
    ov.x = O[j4 * 4 + 0] * inv; ov.y = O[j4 * 4 + 1] * inv;
    ov.z = O[j4 * 4 + 2] * inv; ov.w = O[j4 * 4 + 3] * inv;
    *(float4*)(o + ob + j4 * 4) = ov;
  }
}

// ---------------- Router: logits->softmax->top2 + expert counts ----------------
__global__ __launch_bounds__(64) void gate_topk(
    const float* __restrict__ hn, const float* __restrict__ Wgate,
    float* __restrict__ topk_p, int* __restrict__ topk_i, int* __restrict__ counts) {
  int t = blockIdx.x, lane = threadIdx.x;
  float acc[8] = {};
  for (int i = lane; i < 1024; i += 64) {
    float xv = hn[(size_t)t * 1024 + i];
    const float4 w0 = *(const float4*)(Wgate + i * 8);
    const float4 w1 = *(const float4*)(Wgate + i * 8 + 4);
    acc[0] += xv * w0.x; acc[1] += xv * w0.y; acc[2] += xv * w0.z; acc[3] += xv * w0.w;
    acc[4] += xv * w1.x; acc[5] += xv * w1.y; acc[6] += xv * w1.z; acc[7] += xv * w1.w;
  }
#pragma unroll
  for (int e = 0; e < 8; ++e)
#pragma unroll
    for (int off = 32; off > 0; off >>= 1) acc[e] += __shfl_down(acc[e], off);
  if (lane == 0) {
    float m = acc[0];
#pragma unroll
    for (int e = 1; e < 8; ++e) m = fmaxf(m, acc[e]);
    float p[8], s = 0.0f;
#pragma unroll
    for (int e = 0; e < 8; ++e) { p[e] = __expf(acc[e] - m); s += p[e]; }
    float invs = 1.0f / s;
#pragma unroll
    for (int e = 0; e < 8; ++e) p[e] *= invs;
    int i1 = 0;
#pragma unroll
    for (int e = 1; e < 8; ++e) if (p[e] > p[i1]) i1 = e;
    int i2 = (i1 == 0) ? 1 : 0;
#pragma unroll
    for (int e = 0; e < 8; ++e) if (e != i1 && p[e] > p[i2]) i2 = e;
    topk_i[t * 2] = i1;     topk_p[t * 2] = p[i1];
    topk_i[t * 2 + 1] = i2; topk_p[t * 2 + 1] = p[i2];
    atomicAdd(&counts[i1], 1);
    atomicAdd(&counts[i2], 1);
  }
}

__global__ void moe_init(int* __restrict__ pair_token, int* __restrict__ counts) {
  int i = blockIdx.x * 256 + threadIdx.x;
  if (i < MAXROWS) pair_token[i] = -1;
  if (i < NEXP) counts[i] = 0;
}

__global__ void moe_prefix(const int* __restrict__ counts, int* __restrict__ seg_off,
                           int* __restrict__ cursor, int* __restrict__ tile_expert) {
  if (threadIdx.x == 0 && blockIdx.x == 0) {
    int so[9];
    int off = 0;
    for (int e = 0; e < 8; ++e) {
      so[e] = off; seg_off[e] = off; cursor[e] = 0;
      off += (counts[e] + 63) & ~63;
    }
    so[8] = off; seg_off[8] = off;
    for (int i = 0; i < MAXTILES; ++i) {
      int row = i * 64, e = -1;
      for (int x = 0; x < 8; ++x)
        if (row >= so[x] && row < so[x + 1]) e = x;
      tile_expert[i] = e;
    }
  }
}

__global__ void moe_scatter(const int* __restrict__ topk_i, const int* __restrict__ seg_off,
                            int* __restrict__ cursor, int* __restrict__ pair_token,
                            int* __restrict__ slot_idx) {
  int idx = blockIdx.x * 256 + threadIdx.x;
  if (idx >= T_TOK * 2) return;
  int e = topk_i[idx];
  int slot = seg_off[e] + atomicAdd(&cursor[e], 1);
  pair_token[slot] = idx >> 1;
  slot_idx[idx] = slot;
}

// ---------------- MoE GEMM1: act = silu(x@Wg) * (x@Wu), gathered rows ----------------
__global__ __launch_bounds__(256) void moe_gemm1(
    const float* __restrict__ hn, const float* __restrict__ Wg, const float* __restrict__ Wu,
    const int* __restrict__ pair_token, const int* __restrict__ tile_expert,
    float* __restrict__ act) {
  const int tm = blockIdx.y;
  const int e = tile_expert[tm];
  if (e < 0) return;
  const float* Bg = Wg + (size_t)e * (H_DIM * FF);
  const float* Bu = Wu + (size_t)e * (H_DIM * FF);
  __shared__ float As[16][68];
  __shared__ float Bgs[16][64];
  __shared__ float Bus[16][64];
  __shared__ int toks[64];
  const int tid = threadIdx.x;
  if (tid < 64) toks[tid] = pair_token[tm * 64 + tid];
  __syncthreads();
  const int col0 = blockIdx.x * 64;
  const int tx = tid & 15, ty = tid >> 4;
  const int aM = tid >> 2, aK = (tid & 3) * 4;
  const int bK = tid >> 4, bN = (tid & 15) * 4;
  const int tokA = toks[aM];
  float accg[4][4] = {}, accu[4][4] = {};
  for (int k0 = 0; k0 < H_DIM; k0 += 16) {
    float4 av = make_float4(0.f, 0.f, 0.f, 0.f);
    if (tokA >= 0) av = *(const float4*)(hn + (size_t)tokA * H_DIM + k0 + aK);
    As[aK + 0][aM] = av.x; As[aK + 1][aM] = av.y;
    As[aK + 2][aM] = av.z; As[aK + 3][aM] = av.w;
    *(float4*)(&Bgs[bK][bN]) = *(const float4*)(Bg + (size_t)(k0 + bK) * FF + col0 + bN);
    *(float4*)(&Bus[bK][bN]) = *(const float4*)(Bu + (size_t)(k0 + bK) * FF + col0 + bN);
    __syncthreads();
#pragma unroll
    for (int kk = 0; kk < 16; ++kk) {
      float4 a = *(const float4*)(&As[kk][ty * 4]);
      float4 g = *(const float4*)(&Bgs[kk][tx * 4]);
      float4 u = *(const float4*)(&Bus[kk][tx * 4]);
      float ar[4] = {a.x, a.y, a.z, a.w};
      float gr[4] = {g.x, g.y, g.z, g.w};
      float ur[4] = {u.x, u.y, u.z, u.w};
#pragma unroll
      for (int i = 0; i < 4; ++i)
#pragma unroll
        for (int j = 0; j < 4; ++j) {
          accg[i][j] += ar[i] * gr[j];
          accu[i][j] += ar[i] * ur[j];
        }
    }
    __syncthreads();
  }
#pragma unroll
  for (int i = 0; i < 4; ++i) {
    float4 o;
    float vals[4];
#pragma unroll
    for (int j = 0; j < 4; ++j) {
      float g = accg[i][j], u = accu[i][j];
      vals[j] = (g * u) / (1.0f + __expf(-g));  // silu(g)*u
    }
    o.x = vals[0]; o.y = vals[1]; o.z = vals[2]; o.w = vals[3];
    *(float4*)(act + (size_t)(tm * 64 + ty * 4 + i) * FF + col0 + tx * 4) = o;
  }
}

// ---------------- MoE GEMM2: pair_out = act @ Wd[e] ----------------
__global__ __launch_bounds__(256) void moe_gemm2(
    const float* __restrict__ act, const float* __restrict__ Wd,
    const int* __restrict__ tile_expert, float* __restrict__ pair_out) {
  const int tm = blockIdx.y;
  const int e = tile_expert[tm];
  if (e < 0) return;
  const float* B = Wd + (size_t)e * (FF * H_DIM);
  __shared__ float As[16][68];
  __shared__ float Bs[16][64];
  const int tid = threadIdx.x;
  const int col0 = blockIdx.x * 64;
  const int tx = tid & 15, ty = tid >> 4;
  const int aM = tid >> 2, aK = (tid & 3) * 4;
  const int bK = tid >> 4, bN = (tid & 15) * 4;
  float acc[4][4] = {};
  for (int k0 = 0; k0 < FF; k0 += 16) {
    float4 av = *(const float4*)(act + (size_t)(tm * 64 + aM) * FF + k0 + aK);
    As[aK + 0][aM] = av.x; As[aK + 1][aM] = av.y;
    As[aK + 2][aM] = av.z; As[aK + 3][aM] = av.w;
    *(float4*)(&Bs[bK][bN]) = *(const float4*)(B + (size_t)(k0 + bK) * H_DIM + col0 + bN);
    __syncthreads();
#pragma unroll
    for (int kk = 0; kk < 16; ++kk) {
      float4 a = *(const float4*)(&As[kk][ty * 4]);
      float4 b = *(const float4*)(&Bs[kk][tx * 4]);
      float ar[4] = {a.x, a.y, a.z, a.w};
      float br[4] = {b.x, b.y, b.z, b.w};
#pragma unroll
      for (int i = 0; i < 4; ++i)
#pragma unroll
        for (int j = 0; j < 4; ++j) acc[i][j] += ar[i] * br[j];
    }
    __syncthreads();
  }
#pragma unroll
  for (int i = 0; i < 4; ++i) {
    float4 o;
    o.x = acc[i][0]; o.y = acc[i][1]; o.z = acc[i][2]; o.w = acc[i][3];
    *(float4*)(pair_out + (size_t)(tm * 64 + ty * 4 + i) * H_DIM + col0 + tx * 4) = o;
  }
}

// ---------------- Final: out = h + sum_k p_k * pair_out[slot_k] ----------------
__global__ __launch_bounds__(256) void final_combine(
    const float* __restrict__ hbuf, const float* __restrict__ pair_out,
    const int* __restrict__ slot_idx, const float* __restrict__ topk_p,
    float* __restrict__ out) {
  int t = blockIdx.x, d = threadIdx.x;
  int s0 = slot_idx[t * 2], s1 = slot_idx[t * 2 + 1];
  float p0 = topk_p[t * 2], p1 = topk_p[t * 2 + 1];
  float4 hv = *(const float4*)(hbuf + (size_t)t * 1024 + d * 4);
  float4 a = *(const float4*)(pair_out + (size_t)s0 * 1024 + d * 4);
  float4 b = *(const float4*)(pair_out + (size_t)s1 * 1024 + d * 4);
  float4 o;
  o.x = hv.x + p0 * a.x + p1 * b.x;
  o.y = hv.y + p0 * a.y + p1 * b.y;
  o.z = hv.z + p0 * a.z + p1 * b.z;
  o.w = hv.w + p0 * a.w + p1 * b.w;
  *(float4*)(out + (size_t)t * 1024 + d * 4) = o;
}

extern "C" void kernel_launch(void* const* d_in, const int* in_sizes, int n_in,
                              void* d_out, int out_size, void* d_ws, size_t ws_size,
                              hipStream_t stream) {
  const float* x     = (const float*)d_in[0];
  // d_in[1] = attention_mask (pure causal; applied analytically)
  const float* w_ln1 = (const float*)d_in[2];
  const float* w_ln2 = (const float*)d_in[3];
  const float* Wq    = (const float*)d_in[4];
  const float* Wk    = (const float*)d_in[5];
  const float* Wv    = (const float*)d_in[6];
  const float* Wo    = (const float*)d_in[7];
  const float* Wgate = (const float*)d_in[8];
  const float* Wg    = (const float*)d_in[9];
  const float* Wu    = (const float*)d_in[10];
  const float* Wd    = (const float*)d_in[11];
  float* out = (float*)d_out;

  float* f = (float*)d_ws;
  float* xn   = f; f += (size_t)T_TOK * H_DIM;
  float* qbuf = f; f += (size_t)T_TOK * 1024;
  float* kbuf = f; f += (size_t)T_TOK * 256;
  float* vbuf = f; f += (size_t)T_TOK * 256;
  float* aout = f; f += (size_t)T_TOK * 1024;
  float* hbuf = f; f += (size_t)T_TOK * H_DIM;
  float* hn   = f; f += (size_t)T_TOK * H_DIM;
  float* act  = f; f += (size_t)MAXROWS * FF;
  float* pair_out = f; f += (size_t)MAXROWS * H_DIM;
  float* topk_p = f; f += T_TOK * 2;
  int* ip = (int*)f;
  int* topk_i      = ip; ip += T_TOK * 2;
  int* slot_idx    = ip; ip += T_TOK * 2;
  int* pair_token  = ip; ip += MAXROWS;
  int* counts      = ip; ip += 8;
  int* cursor      = ip; ip += 8;
  int* seg_off     = ip; ip += 16;
  int* tile_expert = ip; ip += MAXTILES;

  // 1. xn = rmsnorm(x, w_ln1)
  rmsnorm_kernel<<<T_TOK, 256, 0, stream>>>(x, w_ln1, xn);
  // 2. q/k/v projections
  gemm_f32<false><<<dim3(16, 64), 256, 0, stream>>>(xn, Wq, nullptr, qbuf, T_TOK, 1024, 1024);
  gemm_f32<false><<<dim3(4, 64), 256, 0, stream>>>(xn, Wk, nullptr, kbuf, T_TOK, 256, 1024);
  gemm_f32<false><<<dim3(4, 64), 256, 0, stream>>>(xn, Wv, nullptr, vbuf, T_TOK, 256, 1024);
  // 3. flash attention (causal, GQA)
  attn_kernel<<<dim3(16, NHEAD, 4), 256, 0, stream>>>(qbuf, kbuf, vbuf, aout);
  // 4. h = x + attn @ Wo
  gemm_f32<true><<<dim3(16, 64), 256, 0, stream>>>(aout, Wo, x, hbuf, T_TOK, 1024, 1024);
  // 5. hn = rmsnorm(h, w_ln2)
  rmsnorm_kernel<<<T_TOK, 256, 0, stream>>>(hbuf, w_ln2, hn);
  // 6. routing
  moe_init<<<(MAXROWS + 255) / 256, 256, 0, stream>>>(pair_token, counts);
  gate_topk<<<T_TOK, 64, 0, stream>>>(hn, Wgate, topk_p, topk_i, counts);
  moe_prefix<<<1, 64, 0, stream>>>(counts, seg_off, cursor, tile_expert);
  moe_scatter<<<(T_TOK * 2 + 255) / 256, 256, 0, stream>>>(topk_i, seg_off, cursor,
                                                           pair_token, slot_idx);
  // 7. routed expert FFN
  moe_gemm1<<<dim3(FF / 64, MAXTILES), 256, 0, stream>>>(hn, Wg, Wu, pair_token,
                                                         tile_expert, act);
  moe_gemm2<<<dim3(H_DIM / 64, MAXTILES), 256, 0, stream>>>(act, Wd, tile_expert, pair_out);
  // 8. out = h + combine
  final_combine<<<T_TOK, 256, 0, stream>>>(hbuf, pair_out, slot_idx, topk_p, out);
}

// Round 2
// 1473.088 us; speedup vs baseline: 1.8874x; 1.8874x over previous
//
#include <hip/hip_runtime.h>
#include <hip/hip_bf16.h>
#include <cstdint>

#define T_TOK    4096
#define H_DIM    1024
#define NHEAD    16
#define NKVH     4
#define HDIM     64
#define NEXP     8
#define FF       2048
#define MAXROWS  9216          // 8192 + 8*128 segment padding
#define MAXT128  72            // MAXROWS/128

typedef __attribute__((ext_vector_type(8))) short bf16x8;
typedef __attribute__((ext_vector_type(4))) float f32x4;

__device__ __forceinline__ short f2bf(float f) {
  union { float f; uint32_t u; } v{f};
  uint32_t r = v.u + 0x7FFF + ((v.u >> 16) & 1);
  return (short)(r >> 16);
}
__device__ __forceinline__ float bf2f(short h) {
  union { uint32_t u; float f; } v;
  v.u = ((uint32_t)(unsigned short)h) << 16;
  return v.f;
}

__device__ __forceinline__ void async_copy16(const void* g, void* l) {
  __builtin_amdgcn_global_load_lds(
      (const __attribute__((address_space(1))) unsigned int*)g,
      (__attribute__((address_space(3))) unsigned int*)l, 16, 0, 0);
}

// ---------------- RMSNorm: writes fp32 and/or 3x-bf16 (hi|lo|hi) ----------------
__global__ __launch_bounds__(256) void rmsnorm3_kernel(
    const float* __restrict__ x, const float* __restrict__ w,
    float* __restrict__ out32, short* __restrict__ out3) {
  int t = blockIdx.x, tid = threadIdx.x;
  const float4 xv = *(const float4*)(x + (size_t)t * H_DIM + tid * 4);
  float ss = xv.x * xv.x + xv.y * xv.y + xv.z * xv.z + xv.w * xv.w;
#pragma unroll
  for (int off = 32; off > 0; off >>= 1) ss += __shfl_down(ss, off);
  __shared__ float red[4];
  if ((tid & 63) == 0) red[tid >> 6] = ss;
  __syncthreads();
  float tot = red[0] + red[1] + red[2] + red[3];
  float rs = rsqrtf(tot * (1.0f / 1024.0f) + 1e-6f);
  const float4 wv = *(const float4*)(w + tid * 4);
  float vals[4];
  vals[0] = xv.x * rs * wv.x; vals[1] = xv.y * rs * wv.y;
  vals[2] = xv.z * rs * wv.z; vals[3] = xv.w * rs * wv.w;
  if (out32) {
    float4 o; o.x = vals[0]; o.y = vals[1]; o.z = vals[2]; o.w = vals[3];
    *(float4*)(out32 + (size_t)t * H_DIM + tid * 4) = o;
  }
  if (out3) {
    union { short s[4]; uint2 u; } H, L;
#pragma unroll
    for (int i = 0; i < 4; ++i) {
      H.s[i] = f2bf(vals[i]);
      L.s[i] = f2bf(vals[i] - bf2f(H.s[i]));
    }
    size_t base = (size_t)t * 3072 + tid * 4;
    *(uint2*)(out3 + base) = H.u;
    *(uint2*)(out3 + base + 1024) = L.u;
    *(uint2*)(out3 + base + 2048) = H.u;
  }
}

// ---------------- Weight convert+transpose, 3x (hi|hi|lo) for A3@B3t ----------------
__global__ __launch_bounds__(256) void conv_t3(
    const float* __restrict__ W, short* __restrict__ Wt3, int K, int N) {
  __shared__ float t[32][33];
  int n0 = blockIdx.x * 32, k0 = blockIdx.y * 32;
  int tx = threadIdx.x & 7, ty = threadIdx.x >> 3;
  float4 v = *(const float4*)(W + (size_t)(k0 + ty) * N + n0 + tx * 4);
  t[ty][tx * 4 + 0] = v.x; t[ty][tx * 4 + 1] = v.y;
  t[ty][tx * 4 + 2] = v.z; t[ty][tx * 4 + 3] = v.w;
  __syncthreads();
  union { short s[4]; uint2 u; } H, L;
#pragma unroll
  for (int i = 0; i < 4; ++i) {
    float f = t[tx * 4 + i][ty];
    H.s[i] = f2bf(f);
    L.s[i] = f2bf(f - bf2f(H.s[i]));
  }
  size_t base = (size_t)(n0 + ty) * (3 * K) + k0 + tx * 4;
  *(uint2*)(Wt3 + base) = H.u;
  *(uint2*)(Wt3 + base + K) = H.u;
  *(uint2*)(Wt3 + base + 2 * K) = L.u;
}

// ---------------- Weight convert+transpose, plain bf16 (per-expert via z) ----------------
__global__ __launch_bounds__(256) void conv_t1(
    const float* __restrict__ W, short* __restrict__ Wt, int K, int N) {
  __shared__ float t[32][33];
  const float* Wb = W + (size_t)blockIdx.z * K * N;
  short* Wtb = Wt + (size_t)blockIdx.z * K * N;
  int n0 = blockIdx.x * 32, k0 = blockIdx.y * 32;
  int tx = threadIdx.x & 7, ty = threadIdx.x >> 3;
  float4 v = *(const float4*)(Wb + (size_t)(k0 + ty) * N + n0 + tx * 4);
  t[ty][tx * 4 + 0] = v.x; t[ty][tx * 4 + 1] = v.y;
  t[ty][tx * 4 + 2] = v.z; t[ty][tx * 4 + 3] = v.w;
  __syncthreads();
  union { short s[4]; uint2 u; } H;
#pragma unroll
  for (int i = 0; i < 4; ++i) H.s[i] = f2bf(t[tx * 4 + i][ty]);
  *(uint2*)(Wtb + (size_t)(n0 + ty) * K + k0 + tx * 4) = H.u;
}

// ---------------- bf16 MFMA GEMM: C(fp32) = A[M][K] @ Bt[N][K]^T (+Res) ----------------
// 128x128 tile, BK=64, 256 thr (4 waves, each 4x4 of 16x16 MFMA tiles).
// LDS XOR-swizzled so global_load_lds stays contiguous AND ds_read_b128 is 2-way max.
__global__ __launch_bounds__(256, 2) void gemm_bf16(
    const short* __restrict__ A, const short* __restrict__ Bt,
    const float* __restrict__ Res, float* __restrict__ C,
    int N, int K, const int* __restrict__ tile_expert, long long expert_stride) {
  __shared__ short As[8192];
  __shared__ short Bs[8192];
  const int tid = threadIdx.x;
  const int w = tid >> 6, lane = tid & 63;
  const int row0 = blockIdx.y * 128, col0 = blockIdx.x * 128;
  if (tile_expert) {
    int e = tile_expert[blockIdx.y];
    if (e < 0) return;
    Bt += (size_t)e * expert_stride;
  }
  const int wm = (w & 1) * 64, wn = (w >> 1) * 64;
  const int lcol = lane & 15, quad = lane >> 4;
  const int cbase = w * 256;
  f32x4 acc[4][4];
#pragma unroll
  for (int i = 0; i < 4; ++i)
#pragma unroll
    for (int j = 0; j < 4; ++j) acc[i][j] = (f32x4){0.f, 0.f, 0.f, 0.f};

  for (int k0 = 0; k0 < K; k0 += 64) {
#pragma unroll
    for (int i = 0; i < 4; ++i) {
      int c = cbase + i * 64 + lane;
      int r = c >> 3, cp = c & 7;
      int sc = (cp ^ (r & 7)) * 8;
      async_copy16(A + (size_t)(row0 + r) * K + k0 + sc, As + (size_t)(cbase + i * 64) * 8);
      async_copy16(Bt + (size_t)(col0 + r) * K + k0 + sc, Bs + (size_t)(cbase + i * 64) * 8);
    }
    __syncthreads();
#pragma unroll
    for (int step = 0; step < 2; ++step) {
      bf16x8 a[4], b[4];
#pragma unroll
      for (int t = 0; t < 4; ++t) {
        int m = wm + t * 16 + lcol;
        int q = quad + step * 4;
        a[t] = *(const bf16x8*)&As[(m * 8 + (q ^ (m & 7))) * 8];
        int n = wn + t * 16 + lcol;
        b[t] = *(const bf16x8*)&Bs[(n * 8 + (q ^ (n & 7))) * 8];
      }
#pragma unroll
      for (int mt = 0; mt < 4; ++mt)
#pragma unroll
        for (int nt = 0; nt < 4; ++nt)
          acc[mt][nt] = __builtin_amdgcn_mfma_f32_16x16x32_bf16(a[mt], b[nt], acc[mt][nt], 0, 0, 0);
    }
    __syncthreads();
  }
#pragma unroll
  for (int mt = 0; mt < 4; ++mt)
#pragma unroll
    for (int r = 0; r < 4; ++r) {
      int gr = row0 + wm + mt * 16 + quad * 4 + r;
#pragma unroll
      for (int nt = 0; nt < 4; ++nt) {
        int gc = col0 + wn + nt * 16 + lcol;
        float v = acc[mt][nt][r];
        if (Res) v += Res[(size_t)gr * N + gc];
        C[(size_t)gr * N + gc] = v;
      }
    }
}

// ---------------- MoE GEMM1 (dual-B): act_bf16 = silu(xg@Wg) * (xg@Wu) ----------------
__global__ __launch_bounds__(256, 2) void moe_gemm1_bf16(
    const short* __restrict__ A, const short* __restrict__ Bgt, const short* __restrict__ But,
    const int* __restrict__ tile_expert, short* __restrict__ act) {
  __shared__ short As[8192];
  __shared__ short Bgs[8192];
  __shared__ short Bus[8192];
  const int tid = threadIdx.x;
  const int w = tid >> 6, lane = tid & 63;
  const int row0 = blockIdx.y * 128, col0 = blockIdx.x * 128;
  int e = tile_expert[blockIdx.y];
  if (e < 0) return;
  const short* Bg = Bgt + (size_t)e * (FF * H_DIM);
  const short* Bu = But + (size_t)e * (FF * H_DIM);
  const int wm = (w & 1) * 64, wn = (w >> 1) * 64;
  const int lcol = lane & 15, quad = lane >> 4;
  const int cbase = w * 256;
  const int K = H_DIM;
  f32x4 accg[4][4], accu[4][4];
#pragma unroll
  for (int i = 0; i < 4; ++i)
#pragma unroll
    for (int j = 0; j < 4; ++j) {
      accg[i][j] = (f32x4){0.f, 0.f, 0.f, 0.f};
      accu[i][j] = (f32x4){0.f, 0.f, 0.f, 0.f};
    }
  for (int k0 = 0; k0 < K; k0 += 64) {
#pragma unroll
    for (int i = 0; i < 4; ++i) {
      int c = cbase + i * 64 + lane;
      int r = c >> 3, cp = c & 7;
      int sc = (cp ^ (r & 7)) * 8;
      async_copy16(A + (size_t)(row0 + r) * K + k0 + sc, As + (size_t)(cbase + i * 64) * 8);
      async_copy16(Bg + (size_t)(col0 + r) * K + k0 + sc, Bgs + (size_t)(cbase + i * 64) * 8);
      async_copy16(Bu + (size_t)(col0 + r) * K + k0 + sc, Bus + (size_t)(cbase + i * 64) * 8);
    }
    __syncthreads();
#pragma unroll
    for (int step = 0; step < 2; ++step) {
      bf16x8 a[4], bg[4], bu[4];
#pragma unroll
      for (int t = 0; t < 4; ++t) {
        int m = wm + t * 16 + lcol;
        int q = quad + step * 4;
        a[t] = *(const bf16x8*)&As[(m * 8 + (q ^ (m & 7))) * 8];
        int n = wn + t * 16 + lcol;
        bg[t] = *(const bf16x8*)&Bgs[(n * 8 + (q ^ (n & 7))) * 8];
        bu[t] = *(const bf16x8*)&Bus[(n * 8 + (q ^ (n & 7))) * 8];
      }
#pragma unroll
      for (int mt = 0; mt < 4; ++mt)
#pragma unroll
        for (int nt = 0; nt < 4; ++nt) {
          accg[mt][nt] = __builtin_amdgcn_mfma_f32_16x16x32_bf16(a[mt], bg[nt], accg[mt][nt], 0, 0, 0);
          accu[mt][nt] = __builtin_amdgcn_mfma_f32_16x16x32_bf16(a[mt], bu[nt], accu[mt][nt], 0, 0, 0);
        }
    }
    __syncthreads();
  }
#pragma unroll
  for (int mt = 0; mt < 4; ++mt)
#pragma unroll
    for (int r = 0; r < 4; ++r) {
      int gr = row0 + wm + mt * 16 + quad * 4 + r;
#pragma unroll
      for (int nt = 0; nt < 4; ++nt) {
        int gc = col0 + wn + nt * 16 + lcol;
        float g = accg[mt][nt][r], u = accu[mt][nt][r];
        float val = (g * u) / (1.0f + __expf(-g));
        act[(size_t)gr * FF + gc] = f2bf(val);
      }
    }
}

// ---------------- Flash attention, causal, GQA; writes 3x-bf16 (hi|lo|hi) ----------------
__global__ __launch_bounds__(256) void attn_kernel(
    const float* __restrict__ q, const float* __restrict__ k,
    const float* __restrict__ v, short* __restrict__ aout3) {
  const int qt = blockIdx.x, h = blockIdx.y, b = blockIdx.z;
  const int kvh = h >> 2;
  __shared__ float Qs[64][68];
  __shared__ float KPs[64][68];
  __shared__ float Vs[64][64];
  const int tid = threadIdx.x;
  const int r = tid >> 2, c4 = tid & 3;
#pragma unroll
  for (int l = 0; l < 4; ++l) {
    int idx = tid + l * 256, m = idx >> 4, d4 = idx & 15;
    *(float4*)(&Qs[m][d4 * 4]) =
        *(const float4*)(q + (size_t)(b * 1024 + qt * 64 + m) * 1024 + h * 64 + d4 * 4);
  }
  float m_i = -3.0e38f, l_i = 0.0f;
  float O[16];
#pragma unroll
  for (int j = 0; j < 16; ++j) O[j] = 0.0f;
  const int qi = qt * 64 + r;

  for (int kt = 0; kt <= qt; ++kt) {
#pragma unroll
    for (int l = 0; l < 4; ++l) {
      int idx = tid + l * 256, m = idx >> 4, d4 = idx & 15;
      size_t base = (size_t)(b * 1024 + kt * 64 + m) * 256 + kvh * 64 + d4 * 4;
      *(float4*)(&KPs[m][d4 * 4]) = *(const float4*)(k + base);
      *(float4*)(&Vs[m][d4 * 4]) = *(const float4*)(v + base);
    }
    __syncthreads();
    float s[16];
#pragma unroll
    for (int j = 0; j < 16; ++j) s[j] = 0.0f;
#pragma unroll 4
    for (int d4 = 0; d4 < 16; ++d4) {
      float4 qv = *(const float4*)(&Qs[r][d4 * 4]);
#pragma unroll
      for (int j = 0; j < 16; ++j) {
        float4 kv = *(const float4*)(&KPs[c4 * 16 + j][d4 * 4]);
        s[j] += qv.x * kv.x + qv.y * kv.y + qv.z * kv.z + qv.w * kv.w;
      }
    }
    const int kbase = kt * 64 + c4 * 16;
#pragma unroll
    for (int j = 0; j < 16; ++j) {
      s[j] *= 0.125f;
      if (kbase + j > qi) s[j] = -3.0e38f;
    }
    float mx = s[0];
#pragma unroll
    for (int j = 1; j < 16; ++j) mx = fmaxf(mx, s[j]);
    mx = fmaxf(mx, __shfl_xor(mx, 1));
    mx = fmaxf(mx, __shfl_xor(mx, 2));
    float m_new = fmaxf(m_i, mx);
    float p[16], rs = 0.0f;
#pragma unroll
    for (int j = 0; j < 16; ++j) { p[j] = __expf(s[j] - m_new); rs += p[j]; }
    rs += __shfl_xor(rs, 1);
    rs += __shfl_xor(rs, 2);
    float alpha = __expf(m_i - m_new);
    l_i = l_i * alpha + rs;
    m_i = m_new;
#pragma unroll
    for (int j = 0; j < 16; ++j) O[j] *= alpha;
    __syncthreads();
#pragma unroll
    for (int j4 = 0; j4 < 4; ++j4) {
      float4 pv;
      pv.x = p[j4 * 4 + 0]; pv.y = p[j4 * 4 + 1];
      pv.z = p[j4 * 4 + 2]; pv.w = p[j4 * 4 + 3];
      *(float4*)(&KPs[r][c4 * 16 + j4 * 4]) = pv;
    }
    __syncthreads();
#pragma unroll 8
    for (int kk = 0; kk < 64; ++kk) {
      float pw = KPs[r][kk];
      float4 v0 = *(const float4*)(&Vs[kk][c4 * 16 + 0]);
      float4 v1 = *(const float4*)(&Vs[kk][c4 * 16 + 4]);
      float4 v2 = *(const float4*)(&Vs[kk][c4 * 16 + 8]);
      float4 v3 = *(const float4*)(&Vs[kk][c4 * 16 + 12]);
      O[0] += pw * v0.x; O[1] += pw * v0.y; O[2] += pw * v0.z; O[3] += pw * v0.w;
      O[4] += pw * v1.x; O[5] += pw * v1.y; O[6] += pw * v1.z; O[7] += pw * v1.w;
      O[8] += pw * v2.x; O[9] += pw * v2.y; O[10] += pw * v2.z; O[11] += pw * v2.w;
      O[12] += pw * v3.x; O[13] += pw * v3.y; O[14] += pw * v3.z; O[15] += pw * v3.w;
    }
    __syncthreads();
  }
  float inv = 1.0f / l_i;
  union { short s[8]; bf16x8 v; } Hh[2], Ll[2];
#pragma unroll
  for (int g = 0; g < 2; ++g)
#pragma unroll
    for (int j = 0; j < 8; ++j) {
      float vv = O[g * 8 + j] * inv;
      short hb = f2bf(vv);
      Hh[g].s[j] = hb;
      Ll[g].s[j] = f2bf(vv - bf2f(hb));
    }
  size_t tb = (size_t)(b * 1024 + qt * 64 + r) * 3072 + h * 64 + c4 * 16;
  *(bf16x8*)(aout3 + tb) = Hh[0].v;
  *(bf16x8*)(aout3 + tb + 8) = Hh[1].v;
  *(bf16x8*)(aout3 + tb + 1024) = Ll[0].v;
  *(bf16x8*)(aout3 + tb + 1032) = Ll[1].v;
  *(bf16x8*)(aout3 + tb + 2048) = Hh[0].v;
  *(bf16x8*)(aout3 + tb + 2056) = Hh[1].v;
}

// ---------------- Router ----------------
__global__ __launch_bounds__(64) void gate_topk(
    const float* __restrict__ hn, const float* __restrict__ Wgate,
    float* __restrict__ topk_p, int* __restrict__ topk_i, int* __restrict__ counts) {
  int t = blockIdx.x, lane = threadIdx.x;
  float acc[8] = {};
  for (int i = lane; i < 1024; i += 64) {
    float xv = hn[(size_t)t * 1024 + i];
    const float4 w0 = *(const float4*)(Wgate + i * 8);
    const float4 w1 = *(const float4*)(Wgate + i * 8 + 4);
    acc[0] += xv * w0.x; acc[1] += xv * w0.y; acc[2] += xv * w0.z; acc[3] += xv * w0.w;
    acc[4] += xv * w1.x; acc[5] += xv * w1.y; acc[6] += xv * w1.z; acc[7] += xv * w1.w;
  }
#pragma unroll
  for (int e = 0; e < 8; ++e)
#pragma unroll
    for (int off = 32; off > 0; off >>= 1) acc[e] += __shfl_down(acc[e], off);
  if (lane == 0) {
    float m = acc[0];
#pragma unroll
    for (int e = 1; e < 8; ++e) m = fmaxf(m, acc[e]);
    float p[8], s = 0.0f;
#pragma unroll
    for (int e = 0; e < 8; ++e) { p[e] = __expf(acc[e] - m); s += p[e]; }
    float invs = 1.0f / s;
#pragma unroll
    for (int e = 0; e < 8; ++e) p[e] *= invs;
    int i1 = 0;
#pragma unroll
    for (int e = 1; e < 8; ++e) if (p[e] > p[i1]) i1 = e;
    int i2 = (i1 == 0) ? 1 : 0;
#pragma unroll
    for (int e = 0; e < 8; ++e) if (e != i1 && p[e] > p[i2]) i2 = e;
    topk_i[t * 2] = i1;     topk_p[t * 2] = p[i1];
    topk_i[t * 2 + 1] = i2; topk_p[t * 2 + 1] = p[i2];
    atomicAdd(&counts[i1], 1);
    atomicAdd(&counts[i2], 1);
  }
}

__global__ void moe_init(int* __restrict__ pair_token, int* __restrict__ counts) {
  int i = blockIdx.x * 256 + threadIdx.x;
  if (i < MAXROWS) pair_token[i] = -1;
  if (i < NEXP) counts[i] = 0;
}

__global__ void moe_prefix(const int* __restrict__ counts, int* __restrict__ seg_off,
                           int* __restrict__ cursor, int* __restrict__ tile_expert) {
  if (threadIdx.x == 0 && blockIdx.x == 0) {
    int so[9];
    int off = 0;
    for (int e = 0; e < 8; ++e) {
      so[e] = off; seg_off[e] = off; cursor[e] = 0;
      off += (counts[e] + 127) & ~127;
    }
    so[8] = off; seg_off[8] = off;
    for (int i = 0; i < MAXT128; ++i) {
      int row = i * 128, e = -1;
      for (int x = 0; x < 8; ++x)
        if (row >= so[x] && row < so[x + 1]) e = x;
      tile_expert[i] = e;
    }
  }
}

__global__ void moe_scatter(const int* __restrict__ topk_i, const int* __restrict__ seg_off,
                            int* __restrict__ cursor, int* __restrict__ pair_token,
                            int* __restrict__ slot_idx) {
  int idx = blockIdx.x * 256 + threadIdx.x;
  if (idx >= T_TOK * 2) return;
  int e = topk_i[idx];
  int slot = seg_off[e] + atomicAdd(&cursor[e], 1);
  pair_token[slot] = idx >> 1;
  slot_idx[idx] = slot;
}

// ---------------- Gather routed rows to dense bf16 ----------------
__global__ __launch_bounds__(128) void gather_rows(
    const float* __restrict__ hn, const int* __restrict__ pair_token,
    short* __restrict__ xg) {
  int slot = blockIdx.x, t = threadIdx.x;
  int tok = pair_token[slot];
  union { short s[8]; bf16x8 v; } P;
  if (tok >= 0) {
    const float4 a = *(const float4*)(hn + (size_t)tok * 1024 + t * 8);
    const float4 bb = *(const float4*)(hn + (size_t)tok * 1024 + t * 8 + 4);
    P.s[0] = f2bf(a.x); P.s[1] = f2bf(a.y); P.s[2] = f2bf(a.z); P.s[3] = f2bf(a.w);
    P.s[4] = f2bf(bb.x); P.s[5] = f2bf(bb.y); P.s[6] = f2bf(bb.z); P.s[7] = f2bf(bb.w);
  } else {
#pragma unroll
    for (int i = 0; i < 8; ++i) P.s[i] = 0;
  }
  *(bf16x8*)(xg + (size_t)slot * 1024 + t * 8) = P.v;
}

// ---------------- Final combine ----------------
__global__ __launch_bounds__(256) void final_combine(
    const float* __restrict__ hbuf, const float* __restrict__ pair_out,
    const int* __restrict__ slot_idx, const float* __restrict__ topk_p,
    float* __restrict__ out) {
  int t = blockIdx.x, d = threadIdx.x;
  int s0 = slot_idx[t * 2], s1 = slot_idx[t * 2 + 1];
  float p0 = topk_p[t * 2], p1 = topk_p[t * 2 + 1];
  float4 hv = *(const float4*)(hbuf + (size_t)t * 1024 + d * 4);
  float4 a = *(const float4*)(pair_out + (size_t)s0 * 1024 + d * 4);
  float4 b = *(const float4*)(pair_out + (size_t)s1 * 1024 + d * 4);
  float4 o;
  o.x = hv.x + p0 * a.x + p1 * b.x;
  o.y = hv.y + p0 * a.y + p1 * b.y;
  o.z = hv.z + p0 * a.z + p1 * b.z;
  o.w = hv.w + p0 * a.w + p1 * b.w;
  *(float4*)(out + (size_t)t * 1024 + d * 4) = o;
}

extern "C" void kernel_launch(void* const* d_in, const int* in_sizes, int n_in,
                              void* d_out, int out_size, void* d_ws, size_t ws_size,
                              hipStream_t stream) {
  const float* x     = (const float*)d_in[0];
  const float* w_ln1 = (const float*)d_in[2];
  const float* w_ln2 = (const float*)d_in[3];
  const float* Wq    = (const float*)d_in[4];
  const float* Wk    = (const float*)d_in[5];
  const float* Wv    = (const float*)d_in[6];
  const float* Wo    = (const float*)d_in[7];
  const float* Wgate = (const float*)d_in[8];
  const float* Wg    = (const float*)d_in[9];
  const float* Wu    = (const float*)d_in[10];
  const float* Wd    = (const float*)d_in[11];
  float* out = (float*)d_out;

  char* base = (char*)d_ws;
  // --- region A (hosts pair_out later): xn3 | Wq3t | Wk3t | Wv3t | qbuf ---
  const size_t SZ_XN3  = (size_t)T_TOK * 3072 * 2;   // 25,165,824
  const size_t SZ_WQ3  = (size_t)1024 * 3072 * 2;    //  6,291,456
  const size_t SZ_WKV3 = (size_t)256 * 3072 * 2;     //  1,572,864
  const size_t SZ_Q    = (size_t)T_TOK * 1024 * 4;   // 16,777,216
  short* xn3  = (short*)base;
  short* Wq3t = (short*)(base + SZ_XN3);
  short* Wk3t = (short*)(base + SZ_XN3 + SZ_WQ3);
  short* Wv3t = (short*)(base + SZ_XN3 + SZ_WQ3 + SZ_WKV3);
  float* qbuf = (float*)(base + SZ_XN3 + SZ_WQ3 + 2 * SZ_WKV3);
  float* pair_out = (float*)base;  // alias: needs 37,748,736 <= 51,380,224
  size_t offB = SZ_XN3 + SZ_WQ3 + 2 * SZ_WKV3 + SZ_Q;
  // --- region B (hosts act later): kbuf | vbuf | aout3 | Wo3t ---
  const size_t SZ_KV  = (size_t)T_TOK * 256 * 4;     //  4,194,304
  float* kbuf  = (float*)(base + offB);
  float* vbuf  = (float*)(base + offB + SZ_KV);
  short* aout3 = (short*)(base + offB + 2 * SZ_KV);
  short* Wo3t  = (short*)(base + offB + 2 * SZ_KV + SZ_XN3);
  short* act   = (short*)(base + offB);  // alias: needs 37,748,736 <= 39,845,888
  size_t off2 = offB + 2 * SZ_KV + SZ_XN3 + SZ_WQ3;
  // --- persistent tail ---
  float* hbuf = (float*)(base + off2);                 off2 += (size_t)T_TOK * 1024 * 4;
  float* hn   = (float*)(base + off2);                 off2 += (size_t)T_TOK * 1024 * 4;
  short* xg   = (short*)(base + off2);                 off2 += (size_t)MAXROWS * 1024 * 2;
  short* Wg_t = (short*)(base + off2);                 off2 += (size_t)NEXP * H_DIM * FF * 2;
  short* Wu_t = (short*)(base + off2);                 off2 += (size_t)NEXP * H_DIM * FF * 2;
  short* Wd_t = (short*)(base + off2);                 off2 += (size_t)NEXP * H_DIM * FF * 2;
  float* topk_p = (float*)(base + off2);               off2 += (size_t)T_TOK * 2 * 4;
  int* topk_i      = (int*)(base + off2);              off2 += (size_t)T_TOK * 2 * 4;
  int* slot_idx    = (int*)(base + off2);              off2 += (size_t)T_TOK * 2 * 4;
  int* pair_token  = (int*)(base + off2);              off2 += (size_t)MAXROWS * 4;
  int* counts      = (int*)(base + off2);              off2 += 64;
  int* cursor      = (int*)(base + off2);              off2 += 64;
  int* seg_off     = (int*)(base + off2);              off2 += 64;
  int* tile_expert = (int*)(base + off2);              off2 += 512;

  // weight converts (independent of activations)
  conv_t3<<<dim3(32, 32), 256, 0, stream>>>(Wq, Wq3t, 1024, 1024);
  conv_t3<<<dim3(8, 32), 256, 0, stream>>>(Wk, Wk3t, 1024, 256);
  conv_t3<<<dim3(8, 32), 256, 0, stream>>>(Wv, Wv3t, 1024, 256);
  conv_t3<<<dim3(32, 32), 256, 0, stream>>>(Wo, Wo3t, 1024, 1024);
  conv_t1<<<dim3(64, 32, 8), 256, 0, stream>>>(Wg, Wg_t, 1024, 2048);
  conv_t1<<<dim3(64, 32, 8), 256, 0, stream>>>(Wu, Wu_t, 1024, 2048);
  conv_t1<<<dim3(32, 64, 8), 256, 0, stream>>>(Wd, Wd_t, 2048, 1024);

  // 1. xn3 = rmsnorm(x) in 3x-bf16
  rmsnorm3_kernel<<<T_TOK, 256, 0, stream>>>(x, w_ln1, nullptr, xn3);
  // 2. q/k/v projections (3x-bf16 MFMA, fp32-accurate)
  gemm_bf16<<<dim3(8, 32), 256, 0, stream>>>(xn3, Wq3t, nullptr, qbuf, 1024, 3072, nullptr, 0);
  gemm_bf16<<<dim3(2, 32), 256, 0, stream>>>(xn3, Wk3t, nullptr, kbuf, 256, 3072, nullptr, 0);
  gemm_bf16<<<dim3(2, 32), 256, 0, stream>>>(xn3, Wv3t, nullptr, vbuf, 256, 3072, nullptr, 0);
  // 3. flash attention -> aout3 (3x-bf16)
  attn_kernel<<<dim3(16, NHEAD, 4), 256, 0, stream>>>(qbuf, kbuf, vbuf, aout3);
  // 4. h = x + attn @ Wo
  gemm_bf16<<<dim3(8, 32), 256, 0, stream>>>(aout3, Wo3t, x, hbuf, 1024, 3072, nullptr, 0);
  // 5. hn = rmsnorm(h) fp32 (routing needs precision)
  rmsnorm3_kernel<<<T_TOK, 256, 0, stream>>>(hbuf, w_ln2, hn, nullptr);
  // 6. routing
  moe_init<<<(MAXROWS + 255) / 256, 256, 0, stream>>>(pair_token, counts);
  gate_topk<<<T_TOK, 64, 0, stream>>>(hn, Wgate, topk_p, topk_i, counts);
  moe_prefix<<<1, 64, 0, stream>>>(counts, seg_off, cursor, tile_expert);
  moe_scatter<<<(T_TOK * 2 + 255) / 256, 256, 0, stream>>>(topk_i, seg_off, cursor,
                                                           pair_token, slot_idx);
  // 7. gather routed rows -> dense bf16
  gather_rows<<<MAXROWS, 128, 0, stream>>>(hn, pair_token, xg);
  // 8. expert FFN (bf16 MFMA)
  moe_gemm1_bf16<<<dim3(16, MAXT128), 256, 0, stream>>>(xg, Wg_t, Wu_t, tile_expert, act);
  gemm_bf16<<<dim3(8, MAXT128), 256, 0, stream>>>(act, Wd_t, nullptr, pair_out, 1024, 2048,
                                                  tile_expert, (long long)FF * H_DIM);
  // 9. out = h + combine
  final_combine<<<T_TOK, 256, 0, stream>>>(hbuf, pair_out, slot_idx, topk_p, out);
}

// Round 3
// 1111.987 us; speedup vs baseline: 2.5003x; 1.3247x over previous
//
#include <hip/hip_runtime.h>
#include <hip/hip_bf16.h>
#include <cstdint>

#define T_TOK    4096
#define H_DIM    1024
#define NHEAD    16
#define NKVH     4
#define HDIM     64
#define NEXP     8
#define FF       2048
#define MAXROWS  9216          // 8192 + 8*128 segment padding
#define MAXT128  72            // MAXROWS/128

typedef __attribute__((ext_vector_type(8))) short bf16x8;
typedef __attribute__((ext_vector_type(4))) float f32x4;

__device__ __forceinline__ short f2bf(float f) {
  union { float f; uint32_t u; } v{f};
  uint32_t r = v.u + 0x7FFF + ((v.u >> 16) & 1);
  return (short)(r >> 16);
}
__device__ __forceinline__ float bf2f(short h) {
  union { uint32_t u; float f; } v;
  v.u = ((uint32_t)(unsigned short)h) << 16;
  return v.f;
}

__device__ __forceinline__ void async_copy16(const void* g, void* l) {
  __builtin_amdgcn_global_load_lds(
      (const __attribute__((address_space(1))) unsigned int*)g,
      (__attribute__((address_space(3))) unsigned int*)l, 16, 0, 0);
}

// ---------------- RMSNorm: writes fp32 and/or 3x-bf16 (hi|lo|hi) ----------------
__global__ __launch_bounds__(256) void rmsnorm3_kernel(
    const float* __restrict__ x, const float* __restrict__ w,
    float* __restrict__ out32, short* __restrict__ out3) {
  int t = blockIdx.x, tid = threadIdx.x;
  const float4 xv = *(const float4*)(x + (size_t)t * H_DIM + tid * 4);
  float ss = xv.x * xv.x + xv.y * xv.y + xv.z * xv.z + xv.w * xv.w;
#pragma unroll
  for (int off = 32; off > 0; off >>= 1) ss += __shfl_down(ss, off);
  __shared__ float red[4];
  if ((tid & 63) == 0) red[tid >> 6] = ss;
  __syncthreads();
  float tot = red[0] + red[1] + red[2] + red[3];
  float rs = rsqrtf(tot * (1.0f / 1024.0f) + 1e-6f);
  const float4 wv = *(const float4*)(w + tid * 4);
  float vals[4];
  vals[0] = xv.x * rs * wv.x; vals[1] = xv.y * rs * wv.y;
  vals[2] = xv.z * rs * wv.z; vals[3] = xv.w * rs * wv.w;
  if (out32) {
    float4 o; o.x = vals[0]; o.y = vals[1]; o.z = vals[2]; o.w = vals[3];
    *(float4*)(out32 + (size_t)t * H_DIM + tid * 4) = o;
  }
  if (out3) {
    union { short s[4]; uint2 u; } H, L;
#pragma unroll
    for (int i = 0; i < 4; ++i) {
      H.s[i] = f2bf(vals[i]);
      L.s[i] = f2bf(vals[i] - bf2f(H.s[i]));
    }
    size_t base = (size_t)t * 3072 + tid * 4;
    *(uint2*)(out3 + base) = H.u;
    *(uint2*)(out3 + base + 1024) = L.u;
    *(uint2*)(out3 + base + 2048) = H.u;
  }
}

// ---------------- Weight convert+transpose, 3x (hi|hi|lo) for A3@B3t ----------------
__global__ __launch_bounds__(256) void conv_t3(
    const float* __restrict__ W, short* __restrict__ Wt3, int K, int N) {
  __shared__ float t[32][33];
  int n0 = blockIdx.x * 32, k0 = blockIdx.y * 32;
  int tx = threadIdx.x & 7, ty = threadIdx.x >> 3;
  float4 v = *(const float4*)(W + (size_t)(k0 + ty) * N + n0 + tx * 4);
  t[ty][tx * 4 + 0] = v.x; t[ty][tx * 4 + 1] = v.y;
  t[ty][tx * 4 + 2] = v.z; t[ty][tx * 4 + 3] = v.w;
  __syncthreads();
  union { short s[4]; uint2 u; } H, L;
#pragma unroll
  for (int i = 0; i < 4; ++i) {
    float f = t[tx * 4 + i][ty];
    H.s[i] = f2bf(f);
    L.s[i] = f2bf(f - bf2f(H.s[i]));
  }
  size_t base = (size_t)(n0 + ty) * (3 * K) + k0 + tx * 4;
  *(uint2*)(Wt3 + base) = H.u;
  *(uint2*)(Wt3 + base + K) = H.u;
  *(uint2*)(Wt3 + base + 2 * K) = L.u;
}

// ---------------- Weight convert+transpose, plain bf16 (per-expert via z) ----------------
__global__ __launch_bounds__(256) void conv_t1(
    const float* __restrict__ W, short* __restrict__ Wt, int K, int N) {
  __shared__ float t[32][33];
  const float* Wb = W + (size_t)blockIdx.z * K * N;
  short* Wtb = Wt + (size_t)blockIdx.z * K * N;
  int n0 = blockIdx.x * 32, k0 = blockIdx.y * 32;
  int tx = threadIdx.x & 7, ty = threadIdx.x >> 3;
  float4 v = *(const float4*)(Wb + (size_t)(k0 + ty) * N + n0 + tx * 4);
  t[ty][tx * 4 + 0] = v.x; t[ty][tx * 4 + 1] = v.y;
  t[ty][tx * 4 + 2] = v.z; t[ty][tx * 4 + 3] = v.w;
  __syncthreads();
  union { short s[4]; uint2 u; } H;
#pragma unroll
  for (int i = 0; i < 4; ++i) H.s[i] = f2bf(t[tx * 4 + i][ty]);
  *(uint2*)(Wtb + (size_t)(n0 + ty) * K + k0 + tx * 4) = H.u;
}

// ---------------- bf16 MFMA GEMM: C(fp32) = A[M][K] @ Bt[N][K]^T (+Res) ----------------
__global__ __launch_bounds__(256, 2) void gemm_bf16(
    const short* __restrict__ A, const short* __restrict__ Bt,
    const float* __restrict__ Res, float* __restrict__ C,
    int N, int K, const int* __restrict__ tile_expert, long long expert_stride) {
  __shared__ short As[8192];
  __shared__ short Bs[8192];
  const int tid = threadIdx.x;
  const int w = tid >> 6, lane = tid & 63;
  const int row0 = blockIdx.y * 128, col0 = blockIdx.x * 128;
  if (tile_expert) {
    int e = tile_expert[blockIdx.y];
    if (e < 0) return;
    Bt += (size_t)e * expert_stride;
  }
  const int wm = (w & 1) * 64, wn = (w >> 1) * 64;
  const int lcol = lane & 15, quad = lane >> 4;
  const int cbase = w * 256;
  f32x4 acc[4][4];
#pragma unroll
  for (int i = 0; i < 4; ++i)
#pragma unroll
    for (int j = 0; j < 4; ++j) acc[i][j] = (f32x4){0.f, 0.f, 0.f, 0.f};

  for (int k0 = 0; k0 < K; k0 += 64) {
#pragma unroll
    for (int i = 0; i < 4; ++i) {
      int c = cbase + i * 64 + lane;
      int r = c >> 3, cp = c & 7;
      int sc = (cp ^ (r & 7)) * 8;
      async_copy16(A + (size_t)(row0 + r) * K + k0 + sc, As + (size_t)(cbase + i * 64) * 8);
      async_copy16(Bt + (size_t)(col0 + r) * K + k0 + sc, Bs + (size_t)(cbase + i * 64) * 8);
    }
    __syncthreads();
#pragma unroll
    for (int step = 0; step < 2; ++step) {
      bf16x8 a[4], b[4];
#pragma unroll
      for (int t = 0; t < 4; ++t) {
        int m = wm + t * 16 + lcol;
        int q = quad + step * 4;
        a[t] = *(const bf16x8*)&As[(m * 8 + (q ^ (m & 7))) * 8];
        int n = wn + t * 16 + lcol;
        b[t] = *(const bf16x8*)&Bs[(n * 8 + (q ^ (n & 7))) * 8];
      }
#pragma unroll
      for (int mt = 0; mt < 4; ++mt)
#pragma unroll
        for (int nt = 0; nt < 4; ++nt)
          acc[mt][nt] = __builtin_amdgcn_mfma_f32_16x16x32_bf16(a[mt], b[nt], acc[mt][nt], 0, 0, 0);
    }
    __syncthreads();
  }
#pragma unroll
  for (int mt = 0; mt < 4; ++mt)
#pragma unroll
    for (int r = 0; r < 4; ++r) {
      int gr = row0 + wm + mt * 16 + quad * 4 + r;
#pragma unroll
      for (int nt = 0; nt < 4; ++nt) {
        int gc = col0 + wn + nt * 16 + lcol;
        float v = acc[mt][nt][r];
        if (Res) v += Res[(size_t)gr * N + gc];
        C[(size_t)gr * N + gc] = v;
      }
    }
}

// ---------------- MoE GEMM1 (dual-B): act_bf16 = silu(xg@Wg) * (xg@Wu) ----------------
__global__ __launch_bounds__(256, 2) void moe_gemm1_bf16(
    const short* __restrict__ A, const short* __restrict__ Bgt, const short* __restrict__ But,
    const int* __restrict__ tile_expert, short* __restrict__ act) {
  __shared__ short As[8192];
  __shared__ short Bgs[8192];
  __shared__ short Bus[8192];
  const int tid = threadIdx.x;
  const int w = tid >> 6, lane = tid & 63;
  const int row0 = blockIdx.y * 128, col0 = blockIdx.x * 128;
  int e = tile_expert[blockIdx.y];
  if (e < 0) return;
  const short* Bg = Bgt + (size_t)e * (FF * H_DIM);
  const short* Bu = But + (size_t)e * (FF * H_DIM);
  const int wm = (w & 1) * 64, wn = (w >> 1) * 64;
  const int lcol = lane & 15, quad = lane >> 4;
  const int cbase = w * 256;
  const int K = H_DIM;
  f32x4 accg[4][4], accu[4][4];
#pragma unroll
  for (int i = 0; i < 4; ++i)
#pragma unroll
    for (int j = 0; j < 4; ++j) {
      accg[i][j] = (f32x4){0.f, 0.f, 0.f, 0.f};
      accu[i][j] = (f32x4){0.f, 0.f, 0.f, 0.f};
    }
  for (int k0 = 0; k0 < K; k0 += 64) {
#pragma unroll
    for (int i = 0; i < 4; ++i) {
      int c = cbase + i * 64 + lane;
      int r = c >> 3, cp = c & 7;
      int sc = (cp ^ (r & 7)) * 8;
      async_copy16(A + (size_t)(row0 + r) * K + k0 + sc, As + (size_t)(cbase + i * 64) * 8);
      async_copy16(Bg + (size_t)(col0 + r) * K + k0 + sc, Bgs + (size_t)(cbase + i * 64) * 8);
      async_copy16(Bu + (size_t)(col0 + r) * K + k0 + sc, Bus + (size_t)(cbase + i * 64) * 8);
    }
    __syncthreads();
#pragma unroll
    for (int step = 0; step < 2; ++step) {
      bf16x8 a[4], bg[4], bu[4];
#pragma unroll
      for (int t = 0; t < 4; ++t) {
        int m = wm + t * 16 + lcol;
        int q = quad + step * 4;
        a[t] = *(const bf16x8*)&As[(m * 8 + (q ^ (m & 7))) * 8];
        int n = wn + t * 16 + lcol;
        bg[t] = *(const bf16x8*)&Bgs[(n * 8 + (q ^ (n & 7))) * 8];
        bu[t] = *(const bf16x8*)&Bus[(n * 8 + (q ^ (n & 7))) * 8];
      }
#pragma unroll
      for (int mt = 0; mt < 4; ++mt)
#pragma unroll
        for (int nt = 0; nt < 4; ++nt) {
          accg[mt][nt] = __builtin_amdgcn_mfma_f32_16x16x32_bf16(a[mt], bg[nt], accg[mt][nt], 0, 0, 0);
          accu[mt][nt] = __builtin_amdgcn_mfma_f32_16x16x32_bf16(a[mt], bu[nt], accu[mt][nt], 0, 0, 0);
        }
    }
    __syncthreads();
  }
#pragma unroll
  for (int mt = 0; mt < 4; ++mt)
#pragma unroll
    for (int r = 0; r < 4; ++r) {
      int gr = row0 + wm + mt * 16 + quad * 4 + r;
#pragma unroll
      for (int nt = 0; nt < 4; ++nt) {
        int gc = col0 + wn + nt * 16 + lcol;
        float g = accg[mt][nt][r], u = accu[mt][nt][r];
        float val = (g * u) / (1.0f + __expf(-g));
        act[(size_t)gr * FF + gc] = f2bf(val);
      }
    }
}

// ---------------- Flash attention (fp32 VALU, register micro-tiles) ----------------
// 128 threads, q-tile 64, k-tile 64. Thread (qr=tid>>3, kgrp=tid&7):
//   QK: rows {qi*16+qr}, keys {kk*8+kgrp}  -> all LDS reads land on 8 bank groups.
//   PV: rows {qi*16+qr}, dims {kgrp*8..+7}.
// P-write -> PV-read stays within one wave (rows depend only on qr) => no barrier.
// 2 syncthreads per k-tile; K/V prefetched to regs one tile ahead.
__global__ __launch_bounds__(128) void attn_kernel(
    const float* __restrict__ q, const float* __restrict__ k,
    const float* __restrict__ v, short* __restrict__ aout3) {
  // qt permutation: co-resident blocks (idx, idx+256, +512, +768) get causal work summing ~const
  const int QTMAP[16] = {0, 2, 4, 6, 15, 13, 11, 9, 1, 3, 5, 7, 14, 12, 10, 8};
  const int bh = blockIdx.x & 63;
  const int z = blockIdx.x >> 6;
  const int qt = QTMAP[z];
  const int b = bh >> 4, h = bh & 15, kvh = h >> 2;
  __shared__ float Qs[64 * 68];
  __shared__ float KPs[64 * 68];  // K tile, then reused as P tile
  __shared__ float Vs[64 * 68];
  const int tid = threadIdx.x;
  const int kgrp = tid & 7;
  const int qr = tid >> 3;  // 0..15
  const float* qbase = q + (size_t)(b * 1024 + qt * 64) * 1024 + h * 64;
#pragma unroll
  for (int l = 0; l < 8; ++l) {
    int idx = tid + l * 128;
    int row = idx >> 4, c4 = idx & 15;
    *(float4*)&Qs[row * 68 + c4 * 4] = *(const float4*)(qbase + (size_t)row * 1024 + c4 * 4);
  }
  const float* kbase = k + (size_t)(b * 1024) * 256 + kvh * 64;
  const float* vbase = v + (size_t)(b * 1024) * 256 + kvh * 64;
  float4 kp[8], vp[8];
#pragma unroll
  for (int l = 0; l < 8; ++l) {
    int idx = tid + l * 128;
    int row = idx >> 4, c4 = idx & 15;
    kp[l] = *(const float4*)(kbase + (size_t)row * 256 + c4 * 4);
    vp[l] = *(const float4*)(vbase + (size_t)row * 256 + c4 * 4);
  }
  float m_i[4], l_i[4], O[4][8];
#pragma unroll
  for (int qi = 0; qi < 4; ++qi) {
    m_i[qi] = -1e30f; l_i[qi] = 0.f;
#pragma unroll
    for (int j = 0; j < 8; ++j) O[qi][j] = 0.f;
  }
  for (int kt = 0; kt <= qt; ++kt) {
    __syncthreads();  // prior PV reads of KPs/Vs complete
#pragma unroll
    for (int l = 0; l < 8; ++l) {
      int idx = tid + l * 128;
      int row = idx >> 4, c4 = idx & 15;
      *(float4*)&KPs[row * 68 + c4 * 4] = kp[l];
      *(float4*)&Vs[row * 68 + c4 * 4] = vp[l];
    }
    __syncthreads();
    if (kt < qt) {
      const float* kb2 = kbase + (size_t)(kt + 1) * 64 * 256;
      const float* vb2 = vbase + (size_t)(kt + 1) * 64 * 256;
#pragma unroll
      for (int l = 0; l < 8; ++l) {
        int idx = tid + l * 128;
        int row = idx >> 4, c4 = idx & 15;
        kp[l] = *(const float4*)(kb2 + (size_t)row * 256 + c4 * 4);
        vp[l] = *(const float4*)(vb2 + (size_t)row * 256 + c4 * 4);
      }
    }
    // QK^T micro-tile
    float S[4][8];
#pragma unroll
    for (int qi = 0; qi < 4; ++qi)
#pragma unroll
      for (int kk = 0; kk < 8; ++kk) S[qi][kk] = 0.f;
#pragma unroll 4
    for (int d4 = 0; d4 < 16; ++d4) {
      float4 qv[4], kv[8];
#pragma unroll
      for (int qi = 0; qi < 4; ++qi)
        qv[qi] = *(const float4*)&Qs[(qi * 16 + qr) * 68 + d4 * 4];
#pragma unroll
      for (int kk = 0; kk < 8; ++kk)
        kv[kk] = *(const float4*)&KPs[(kk * 8 + kgrp) * 68 + d4 * 4];
#pragma unroll
      for (int qi = 0; qi < 4; ++qi)
#pragma unroll
        for (int kk = 0; kk < 8; ++kk)
          S[qi][kk] += qv[qi].x * kv[kk].x + qv[qi].y * kv[kk].y +
                       qv[qi].z * kv[kk].z + qv[qi].w * kv[kk].w;
    }
    // online softmax per row (8-lane kgrp group shares a row)
    const bool diag = (kt == qt);
#pragma unroll
    for (int qi = 0; qi < 4; ++qi) {
      int rl = qi * 16 + qr;  // local row == local key bound on diagonal tile
      float mx = -1e30f;
#pragma unroll
      for (int kk = 0; kk < 8; ++kk) {
        S[qi][kk] *= 0.125f;
        if (diag && (kk * 8 + kgrp) > rl) S[qi][kk] = -1e30f;
        mx = fmaxf(mx, S[qi][kk]);
      }
      mx = fmaxf(mx, __shfl_xor(mx, 1));
      mx = fmaxf(mx, __shfl_xor(mx, 2));
      mx = fmaxf(mx, __shfl_xor(mx, 4));
      float m_new = fmaxf(m_i[qi], mx);
      float rs = 0.f;
#pragma unroll
      for (int kk = 0; kk < 8; ++kk) {
        S[qi][kk] = __expf(S[qi][kk] - m_new);
        rs += S[qi][kk];
      }
      rs += __shfl_xor(rs, 1);
      rs += __shfl_xor(rs, 2);
      rs += __shfl_xor(rs, 4);
      float alpha = __expf(m_i[qi] - m_new);
      l_i[qi] = l_i[qi] * alpha + rs;
      m_i[qi] = m_new;
#pragma unroll
      for (int j = 0; j < 8; ++j) O[qi][j] *= alpha;
    }
    __syncthreads();  // all QK reads of KPs done before overwrite with P
#pragma unroll
    for (int qi = 0; qi < 4; ++qi)
#pragma unroll
      for (int kk = 0; kk < 8; ++kk)
        KPs[(qi * 16 + qr) * 68 + kk * 8 + kgrp] = S[qi][kk];
    // PV (P rows we read were written by lanes of our own wave -> lgkmcnt only)
#pragma unroll 2
    for (int k4 = 0; k4 < 16; ++k4) {
      float4 Pv[4];
#pragma unroll
      for (int qi = 0; qi < 4; ++qi)
        Pv[qi] = *(const float4*)&KPs[(qi * 16 + qr) * 68 + k4 * 4];
#pragma unroll
      for (int j = 0; j < 4; ++j) {
        int key = k4 * 4 + j;
        float4 v0 = *(const float4*)&Vs[key * 68 + kgrp * 8];
        float4 v1 = *(const float4*)&Vs[key * 68 + kgrp * 8 + 4];
#pragma unroll
        for (int qi = 0; qi < 4; ++qi) {
          float pw = (j == 0) ? Pv[qi].x : (j == 1) ? Pv[qi].y : (j == 2) ? Pv[qi].z : Pv[qi].w;
          O[qi][0] += pw * v0.x; O[qi][1] += pw * v0.y;
          O[qi][2] += pw * v0.z; O[qi][3] += pw * v0.w;
          O[qi][4] += pw * v1.x; O[qi][5] += pw * v1.y;
          O[qi][6] += pw * v1.z; O[qi][7] += pw * v1.w;
        }
      }
    }
  }
  // epilogue: normalize + 3x-bf16 (hi|lo|hi)
#pragma unroll
  for (int qi = 0; qi < 4; ++qi) {
    float inv = 1.0f / l_i[qi];
    union { short s[8]; bf16x8 v; } Hh, Ll;
#pragma unroll
    for (int j = 0; j < 8; ++j) {
      float vv = O[qi][j] * inv;
      short hb = f2bf(vv);
      Hh.s[j] = hb;
      Ll.s[j] = f2bf(vv - bf2f(hb));
    }
    size_t tb = (size_t)(b * 1024 + qt * 64 + qi * 16 + qr) * 3072 + h * 64 + kgrp * 8;
    *(bf16x8*)(aout3 + tb) = Hh.v;
    *(bf16x8*)(aout3 + tb + 1024) = Ll.v;
    *(bf16x8*)(aout3 + tb + 2048) = Hh.v;
  }
}

// ---------------- Router ----------------
__global__ __launch_bounds__(64) void gate_topk(
    const float* __restrict__ hn, const float* __restrict__ Wgate,
    float* __restrict__ topk_p, int* __restrict__ topk_i, int* __restrict__ counts) {
  int t = blockIdx.x, lane = threadIdx.x;
  float acc[8] = {};
  for (int i = lane; i < 1024; i += 64) {
    float xv = hn[(size_t)t * 1024 + i];
    const float4 w0 = *(const float4*)(Wgate + i * 8);
    const float4 w1 = *(const float4*)(Wgate + i * 8 + 4);
    acc[0] += xv * w0.x; acc[1] += xv * w0.y; acc[2] += xv * w0.z; acc[3] += xv * w0.w;
    acc[4] += xv * w1.x; acc[5] += xv * w1.y; acc[6] += xv * w1.z; acc[7] += xv * w1.w;
  }
#pragma unroll
  for (int e = 0; e < 8; ++e)
#pragma unroll
    for (int off = 32; off > 0; off >>= 1) acc[e] += __shfl_down(acc[e], off);
  if (lane == 0) {
    float m = acc[0];
#pragma unroll
    for (int e = 1; e < 8; ++e) m = fmaxf(m, acc[e]);
    float p[8], s = 0.0f;
#pragma unroll
    for (int e = 0; e < 8; ++e) { p[e] = __expf(acc[e] - m); s += p[e]; }
    float invs = 1.0f / s;
#pragma unroll
    for (int e = 0; e < 8; ++e) p[e] *= invs;
    int i1 = 0;
#pragma unroll
    for (int e = 1; e < 8; ++e) if (p[e] > p[i1]) i1 = e;
    int i2 = (i1 == 0) ? 1 : 0;
#pragma unroll
    for (int e = 0; e < 8; ++e) if (e != i1 && p[e] > p[i2]) i2 = e;
    topk_i[t * 2] = i1;     topk_p[t * 2] = p[i1];
    topk_i[t * 2 + 1] = i2; topk_p[t * 2 + 1] = p[i2];
    atomicAdd(&counts[i1], 1);
    atomicAdd(&counts[i2], 1);
  }
}

__global__ void moe_init(int* __restrict__ pair_token, int* __restrict__ counts) {
  int i = blockIdx.x * 256 + threadIdx.x;
  if (i < MAXROWS) pair_token[i] = -1;
  if (i < NEXP) counts[i] = 0;
}

__global__ void moe_prefix(const int* __restrict__ counts, int* __restrict__ seg_off,
                           int* __restrict__ cursor, int* __restrict__ tile_expert) {
  if (threadIdx.x == 0 && blockIdx.x == 0) {
    int so[9];
    int off = 0;
    for (int e = 0; e < 8; ++e) {
      so[e] = off; seg_off[e] = off; cursor[e] = 0;
      off += (counts[e] + 127) & ~127;
    }
    so[8] = off; seg_off[8] = off;
    for (int i = 0; i < MAXT128; ++i) {
      int row = i * 128, e = -1;
      for (int x = 0; x < 8; ++x)
        if (row >= so[x] && row < so[x + 1]) e = x;
      tile_expert[i] = e;
    }
  }
}

__global__ void moe_scatter(const int* __restrict__ topk_i, const int* __restrict__ seg_off,
                            int* __restrict__ cursor, int* __restrict__ pair_token,
                            int* __restrict__ slot_idx) {
  int idx = blockIdx.x * 256 + threadIdx.x;
  if (idx >= T_TOK * 2) return;
  int e = topk_i[idx];
  int slot = seg_off[e] + atomicAdd(&cursor[e], 1);
  pair_token[slot] = idx >> 1;
  slot_idx[idx] = slot;
}

// ---------------- Gather routed rows to dense bf16 ----------------
__global__ __launch_bounds__(128) void gather_rows(
    const float* __restrict__ hn, const int* __restrict__ pair_token,
    short* __restrict__ xg) {
  int slot = blockIdx.x, t = threadIdx.x;
  int tok = pair_token[slot];
  union { short s[8]; bf16x8 v; } P;
  if (tok >= 0) {
    const float4 a = *(const float4*)(hn + (size_t)tok * 1024 + t * 8);
    const float4 bb = *(const float4*)(hn + (size_t)tok * 1024 + t * 8 + 4);
    P.s[0] = f2bf(a.x); P.s[1] = f2bf(a.y); P.s[2] = f2bf(a.z); P.s[3] = f2bf(a.w);
    P.s[4] = f2bf(bb.x); P.s[5] = f2bf(bb.y); P.s[6] = f2bf(bb.z); P.s[7] = f2bf(bb.w);
  } else {
#pragma unroll
    for (int i = 0; i < 8; ++i) P.s[i] = 0;
  }
  *(bf16x8*)(xg + (size_t)slot * 1024 + t * 8) = P.v;
}

// ---------------- Final combine ----------------
__global__ __launch_bounds__(256) void final_combine(
    const float* __restrict__ hbuf, const float* __restrict__ pair_out,
    const int* __restrict__ slot_idx, const float* __restrict__ topk_p,
    float* __restrict__ out) {
  int t = blockIdx.x, d = threadIdx.x;
  int s0 = slot_idx[t * 2], s1 = slot_idx[t * 2 + 1];
  float p0 = topk_p[t * 2], p1 = topk_p[t * 2 + 1];
  float4 hv = *(const float4*)(hbuf + (size_t)t * 1024 + d * 4);
  float4 a = *(const float4*)(pair_out + (size_t)s0 * 1024 + d * 4);
  float4 b = *(const float4*)(pair_out + (size_t)s1 * 1024 + d * 4);
  float4 o;
  o.x = hv.x + p0 * a.x + p1 * b.x;
  o.y = hv.y + p0 * a.y + p1 * b.y;
  o.z = hv.z + p0 * a.z + p1 * b.z;
  o.w = hv.w + p0 * a.w + p1 * b.w;
  *(float4*)(out + (size_t)t * 1024 + d * 4) = o;
}

extern "C" void kernel_launch(void* const* d_in, const int* in_sizes, int n_in,
                              void* d_out, int out_size, void* d_ws, size_t ws_size,
                              hipStream_t stream) {
  const float* x     = (const float*)d_in[0];
  const float* w_ln1 = (const float*)d_in[2];
  const float* w_ln2 = (const float*)d_in[3];
  const float* Wq    = (const float*)d_in[4];
  const float* Wk    = (const float*)d_in[5];
  const float* Wv    = (const float*)d_in[6];
  const float* Wo    = (const float*)d_in[7];
  const float* Wgate = (const float*)d_in[8];
  const float* Wg    = (const float*)d_in[9];
  const float* Wu    = (const float*)d_in[10];
  const float* Wd    = (const float*)d_in[11];
  float* out = (float*)d_out;

  char* base = (char*)d_ws;
  const size_t SZ_XN3  = (size_t)T_TOK * 3072 * 2;   // 25,165,824
  const size_t SZ_WQ3  = (size_t)1024 * 3072 * 2;    //  6,291,456
  const size_t SZ_WKV3 = (size_t)256 * 3072 * 2;     //  1,572,864
  const size_t SZ_Q    = (size_t)T_TOK * 1024 * 4;   // 16,777,216
  short* xn3  = (short*)base;
  short* Wq3t = (short*)(base + SZ_XN3);
  short* Wk3t = (short*)(base + SZ_XN3 + SZ_WQ3);
  short* Wv3t = (short*)(base + SZ_XN3 + SZ_WQ3 + SZ_WKV3);
  float* qbuf = (float*)(base + SZ_XN3 + SZ_WQ3 + 2 * SZ_WKV3);
  float* pair_out = (float*)base;  // alias region A
  size_t offB = SZ_XN3 + SZ_WQ3 + 2 * SZ_WKV3 + SZ_Q;
  const size_t SZ_KV  = (size_t)T_TOK * 256 * 4;     //  4,194,304
  float* kbuf  = (float*)(base + offB);
  float* vbuf  = (float*)(base + offB + SZ_KV);
  short* aout3 = (short*)(base + offB + 2 * SZ_KV);
  short* Wo3t  = (short*)(base + offB + 2 * SZ_KV + SZ_XN3);
  short* act   = (short*)(base + offB);  // alias region B
  size_t off2 = offB + 2 * SZ_KV + SZ_XN3 + SZ_WQ3;
  float* hbuf = (float*)(base + off2);                 off2 += (size_t)T_TOK * 1024 * 4;
  float* hn   = (float*)(base + off2);                 off2 += (size_t)T_TOK * 1024 * 4;
  short* xg   = (short*)(base + off2);                 off2 += (size_t)MAXROWS * 1024 * 2;
  short* Wg_t = (short*)(base + off2);                 off2 += (size_t)NEXP * H_DIM * FF * 2;
  short* Wu_t = (short*)(base + off2);                 off2 += (size_t)NEXP * H_DIM * FF * 2;
  short* Wd_t = (short*)(base + off2);                 off2 += (size_t)NEXP * H_DIM * FF * 2;
  float* topk_p = (float*)(base + off2);               off2 += (size_t)T_TOK * 2 * 4;
  int* topk_i      = (int*)(base + off2);              off2 += (size_t)T_TOK * 2 * 4;
  int* slot_idx    = (int*)(base + off2);              off2 += (size_t)T_TOK * 2 * 4;
  int* pair_token  = (int*)(base + off2);              off2 += (size_t)MAXROWS * 4;
  int* counts      = (int*)(base + off2);              off2 += 64;
  int* cursor      = (int*)(base + off2);              off2 += 64;
  int* seg_off     = (int*)(base + off2);              off2 += 64;
  int* tile_expert = (int*)(base + off2);              off2 += 512;

  conv_t3<<<dim3(32, 32), 256, 0, stream>>>(Wq, Wq3t, 1024, 1024);
  conv_t3<<<dim3(8, 32), 256, 0, stream>>>(Wk, Wk3t, 1024, 256);
  conv_t3<<<dim3(8, 32), 256, 0, stream>>>(Wv, Wv3t, 1024, 256);
  conv_t3<<<dim3(32, 32), 256, 0, stream>>>(Wo, Wo3t, 1024, 1024);
  conv_t1<<<dim3(64, 32, 8), 256, 0, stream>>>(Wg, Wg_t, 1024, 2048);
  conv_t1<<<dim3(64, 32, 8), 256, 0, stream>>>(Wu, Wu_t, 1024, 2048);
  conv_t1<<<dim3(32, 64, 8), 256, 0, stream>>>(Wd, Wd_t, 2048, 1024);

  rmsnorm3_kernel<<<T_TOK, 256, 0, stream>>>(x, w_ln1, nullptr, xn3);
  gemm_bf16<<<dim3(8, 32), 256, 0, stream>>>(xn3, Wq3t, nullptr, qbuf, 1024, 3072, nullptr, 0);
  gemm_bf16<<<dim3(2, 32), 256, 0, stream>>>(xn3, Wk3t, nullptr, kbuf, 256, 3072, nullptr, 0);
  gemm_bf16<<<dim3(2, 32), 256, 0, stream>>>(xn3, Wv3t, nullptr, vbuf, 256, 3072, nullptr, 0);
  attn_kernel<<<dim3(1024), 128, 0, stream>>>(qbuf, kbuf, vbuf, aout3);
  gemm_bf16<<<dim3(8, 32), 256, 0, stream>>>(aout3, Wo3t, x, hbuf, 1024, 3072, nullptr, 0);
  rmsnorm3_kernel<<<T_TOK, 256, 0, stream>>>(hbuf, w_ln2, hn, nullptr);
  moe_init<<<(MAXROWS + 255) / 256, 256, 0, stream>>>(pair_token, counts);
  gate_topk<<<T_TOK, 64, 0, stream>>>(hn, Wgate, topk_p, topk_i, counts);
  moe_prefix<<<1, 64, 0, stream>>>(counts, seg_off, cursor, tile_expert);
  moe_scatter<<<(T_TOK * 2 + 255) / 256, 256, 0, stream>>>(topk_i, seg_off, cursor,
                                                           pair_token, slot_idx);
  gather_rows<<<MAXROWS, 128, 0, stream>>>(hn, pair_token, xg);
  moe_gemm1_bf16<<<dim3(16, MAXT128), 256, 0, stream>>>(xg, Wg_t, Wu_t, tile_expert, act);
  gemm_bf16<<<dim3(8, MAXT128), 256, 0, stream>>>(act, Wd_t, nullptr, pair_out, 1024, 2048,
                                                  tile_expert, (long long)FF * H_DIM);
  final_combine<<<T_TOK, 256, 0, stream>>>(hbuf, pair_out, slot_idx, topk_p, out);
}

// Round 4
// 921.596 us; speedup vs baseline: 3.0169x; 1.2066x over previous
//
#include <hip/hip_runtime.h>
#include <hip/hip_bf16.h>
#include <cstdint>

#define T_TOK    4096
#define H_DIM    1024
#define NHEAD    16
#define NKVH     4
#define HDIM     64
#define NEXP     8
#define FF       2048
#define MAXROWS  9216          // 8192 + 8*128 segment padding
#define MAXT128  72            // MAXROWS/128

typedef __attribute__((ext_vector_type(8))) short bf16x8;
typedef __attribute__((ext_vector_type(4))) short s16x4;
typedef __attribute__((ext_vector_type(4))) float f32x4;

__device__ __forceinline__ short f2bf(float f) {
  union { float f; uint32_t u; } v{f};
  uint32_t r = v.u + 0x7FFF + ((v.u >> 16) & 1);
  return (short)(r >> 16);
}
__device__ __forceinline__ float bf2f(short h) {
  union { uint32_t u; float f; } v;
  v.u = ((uint32_t)(unsigned short)h) << 16;
  return v.f;
}

__device__ __forceinline__ void async_copy16(const void* g, void* l) {
  __builtin_amdgcn_global_load_lds(
      (const __attribute__((address_space(1))) unsigned int*)g,
      (__attribute__((address_space(3))) unsigned int*)l, 16, 0, 0);
}

// ---------------- RMSNorm: writes fp32 and/or 3x-bf16 (hi|lo|hi) ----------------
__global__ __launch_bounds__(256) void rmsnorm3_kernel(
    const float* __restrict__ x, const float* __restrict__ w,
    float* __restrict__ out32, short* __restrict__ out3) {
  int t = blockIdx.x, tid = threadIdx.x;
  const float4 xv = *(const float4*)(x + (size_t)t * H_DIM + tid * 4);
  float ss = xv.x * xv.x + xv.y * xv.y + xv.z * xv.z + xv.w * xv.w;
#pragma unroll
  for (int off = 32; off > 0; off >>= 1) ss += __shfl_down(ss, off);
  __shared__ float red[4];
  if ((tid & 63) == 0) red[tid >> 6] = ss;
  __syncthreads();
  float tot = red[0] + red[1] + red[2] + red[3];
  float rs = rsqrtf(tot * (1.0f / 1024.0f) + 1e-6f);
  const float4 wv = *(const float4*)(w + tid * 4);
  float vals[4];
  vals[0] = xv.x * rs * wv.x; vals[1] = xv.y * rs * wv.y;
  vals[2] = xv.z * rs * wv.z; vals[3] = xv.w * rs * wv.w;
  if (out32) {
    float4 o; o.x = vals[0]; o.y = vals[1]; o.z = vals[2]; o.w = vals[3];
    *(float4*)(out32 + (size_t)t * H_DIM + tid * 4) = o;
  }
  if (out3) {
    union { short s[4]; uint2 u; } H, L;
#pragma unroll
    for (int i = 0; i < 4; ++i) {
      H.s[i] = f2bf(vals[i]);
      L.s[i] = f2bf(vals[i] - bf2f(H.s[i]));
    }
    size_t base = (size_t)t * 3072 + tid * 4;
    *(uint2*)(out3 + base) = H.u;
    *(uint2*)(out3 + base + 1024) = L.u;
    *(uint2*)(out3 + base + 2048) = H.u;
  }
}

// ---------------- Weight convert+transpose, 3x (hi|hi|lo) for A3@B3t ----------------
__global__ __launch_bounds__(256) void conv_t3(
    const float* __restrict__ W, short* __restrict__ Wt3, int K, int N) {
  __shared__ float t[32][33];
  int n0 = blockIdx.x * 32, k0 = blockIdx.y * 32;
  int tx = threadIdx.x & 7, ty = threadIdx.x >> 3;
  float4 v = *(const float4*)(W + (size_t)(k0 + ty) * N + n0 + tx * 4);
  t[ty][tx * 4 + 0] = v.x; t[ty][tx * 4 + 1] = v.y;
  t[ty][tx * 4 + 2] = v.z; t[ty][tx * 4 + 3] = v.w;
  __syncthreads();
  union { short s[4]; uint2 u; } H, L;
#pragma unroll
  for (int i = 0; i < 4; ++i) {
    float f = t[tx * 4 + i][ty];
    H.s[i] = f2bf(f);
    L.s[i] = f2bf(f - bf2f(H.s[i]));
  }
  size_t base = (size_t)(n0 + ty) * (3 * K) + k0 + tx * 4;
  *(uint2*)(Wt3 + base) = H.u;
  *(uint2*)(Wt3 + base + K) = H.u;
  *(uint2*)(Wt3 + base + 2 * K) = L.u;
}

// ---------------- Weight convert+transpose, plain bf16 (per-expert via z) ----------------
__global__ __launch_bounds__(256) void conv_t1(
    const float* __restrict__ W, short* __restrict__ Wt, int K, int N) {
  __shared__ float t[32][33];
  const float* Wb = W + (size_t)blockIdx.z * K * N;
  short* Wtb = Wt + (size_t)blockIdx.z * K * N;
  int n0 = blockIdx.x * 32, k0 = blockIdx.y * 32;
  int tx = threadIdx.x & 7, ty = threadIdx.x >> 3;
  float4 v = *(const float4*)(Wb + (size_t)(k0 + ty) * N + n0 + tx * 4);
  t[ty][tx * 4 + 0] = v.x; t[ty][tx * 4 + 1] = v.y;
  t[ty][tx * 4 + 2] = v.z; t[ty][tx * 4 + 3] = v.w;
  __syncthreads();
  union { short s[4]; uint2 u; } H;
#pragma unroll
  for (int i = 0; i < 4; ++i) H.s[i] = f2bf(t[tx * 4 + i][ty]);
  *(uint2*)(Wtb + (size_t)(n0 + ty) * K + k0 + tx * 4) = H.u;
}

// ---------------- bf16 MFMA GEMM: C(fp32) = A[M][K] @ Bt[N][K]^T (+Res) ----------------
__global__ __launch_bounds__(256, 2) void gemm_bf16(
    const short* __restrict__ A, const short* __restrict__ Bt,
    const float* __restrict__ Res, float* __restrict__ C,
    int N, int K, const int* __restrict__ tile_expert, long long expert_stride) {
  __shared__ short As[8192];
  __shared__ short Bs[8192];
  const int tid = threadIdx.x;
  const int w = tid >> 6, lane = tid & 63;
  const int row0 = blockIdx.y * 128, col0 = blockIdx.x * 128;
  if (tile_expert) {
    int e = tile_expert[blockIdx.y];
    if (e < 0) return;
    Bt += (size_t)e * expert_stride;
  }
  const int wm = (w & 1) * 64, wn = (w >> 1) * 64;
  const int lcol = lane & 15, quad = lane >> 4;
  const int cbase = w * 256;
  f32x4 acc[4][4];
#pragma unroll
  for (int i = 0; i < 4; ++i)
#pragma unroll
    for (int j = 0; j < 4; ++j) acc[i][j] = (f32x4){0.f, 0.f, 0.f, 0.f};

  for (int k0 = 0; k0 < K; k0 += 64) {
#pragma unroll
    for (int i = 0; i < 4; ++i) {
      int c = cbase + i * 64 + lane;
      int r = c >> 3, cp = c & 7;
      int sc = (cp ^ (r & 7)) * 8;
      async_copy16(A + (size_t)(row0 + r) * K + k0 + sc, As + (size_t)(cbase + i * 64) * 8);
      async_copy16(Bt + (size_t)(col0 + r) * K + k0 + sc, Bs + (size_t)(cbase + i * 64) * 8);
    }
    __syncthreads();
#pragma unroll
    for (int step = 0; step < 2; ++step) {
      bf16x8 a[4], b[4];
#pragma unroll
      for (int t = 0; t < 4; ++t) {
        int m = wm + t * 16 + lcol;
        int q = quad + step * 4;
        a[t] = *(const bf16x8*)&As[(m * 8 + (q ^ (m & 7))) * 8];
        int n = wn + t * 16 + lcol;
        b[t] = *(const bf16x8*)&Bs[(n * 8 + (q ^ (n & 7))) * 8];
      }
#pragma unroll
      for (int mt = 0; mt < 4; ++mt)
#pragma unroll
        for (int nt = 0; nt < 4; ++nt)
          acc[mt][nt] = __builtin_amdgcn_mfma_f32_16x16x32_bf16(a[mt], b[nt], acc[mt][nt], 0, 0, 0);
    }
    __syncthreads();
  }
#pragma unroll
  for (int mt = 0; mt < 4; ++mt)
#pragma unroll
    for (int r = 0; r < 4; ++r) {
      int gr = row0 + wm + mt * 16 + quad * 4 + r;
#pragma unroll
      for (int nt = 0; nt < 4; ++nt) {
        int gc = col0 + wn + nt * 16 + lcol;
        float v = acc[mt][nt][r];
        if (Res) v += Res[(size_t)gr * N + gc];
        C[(size_t)gr * N + gc] = v;
      }
    }
}

// ---------------- MoE GEMM1 (dual-B): act_bf16 = silu(xg@Wg) * (xg@Wu) ----------------
__global__ __launch_bounds__(256, 2) void moe_gemm1_bf16(
    const short* __restrict__ A, const short* __restrict__ Bgt, const short* __restrict__ But,
    const int* __restrict__ tile_expert, short* __restrict__ act) {
  __shared__ short As[8192];
  __shared__ short Bgs[8192];
  __shared__ short Bus[8192];
  const int tid = threadIdx.x;
  const int w = tid >> 6, lane = tid & 63;
  const int row0 = blockIdx.y * 128, col0 = blockIdx.x * 128;
  int e = tile_expert[blockIdx.y];
  if (e < 0) return;
  const short* Bg = Bgt + (size_t)e * (FF * H_DIM);
  const short* Bu = But + (size_t)e * (FF * H_DIM);
  const int wm = (w & 1) * 64, wn = (w >> 1) * 64;
  const int lcol = lane & 15, quad = lane >> 4;
  const int cbase = w * 256;
  const int K = H_DIM;
  f32x4 accg[4][4], accu[4][4];
#pragma unroll
  for (int i = 0; i < 4; ++i)
#pragma unroll
    for (int j = 0; j < 4; ++j) {
      accg[i][j] = (f32x4){0.f, 0.f, 0.f, 0.f};
      accu[i][j] = (f32x4){0.f, 0.f, 0.f, 0.f};
    }
  for (int k0 = 0; k0 < K; k0 += 64) {
#pragma unroll
    for (int i = 0; i < 4; ++i) {
      int c = cbase + i * 64 + lane;
      int r = c >> 3, cp = c & 7;
      int sc = (cp ^ (r & 7)) * 8;
      async_copy16(A + (size_t)(row0 + r) * K + k0 + sc, As + (size_t)(cbase + i * 64) * 8);
      async_copy16(Bg + (size_t)(col0 + r) * K + k0 + sc, Bgs + (size_t)(cbase + i * 64) * 8);
      async_copy16(Bu + (size_t)(col0 + r) * K + k0 + sc, Bus + (size_t)(cbase + i * 64) * 8);
    }
    __syncthreads();
#pragma unroll
    for (int step = 0; step < 2; ++step) {
      bf16x8 a[4], bg[4], bu[4];
#pragma unroll
      for (int t = 0; t < 4; ++t) {
        int m = wm + t * 16 + lcol;
        int q = quad + step * 4;
        a[t] = *(const bf16x8*)&As[(m * 8 + (q ^ (m & 7))) * 8];
        int n = wn + t * 16 + lcol;
        bg[t] = *(const bf16x8*)&Bgs[(n * 8 + (q ^ (n & 7))) * 8];
        bu[t] = *(const bf16x8*)&Bus[(n * 8 + (q ^ (n & 7))) * 8];
      }
#pragma unroll
      for (int mt = 0; mt < 4; ++mt)
#pragma unroll
        for (int nt = 0; nt < 4; ++nt) {
          accg[mt][nt] = __builtin_amdgcn_mfma_f32_16x16x32_bf16(a[mt], bg[nt], accg[mt][nt], 0, 0, 0);
          accu[mt][nt] = __builtin_amdgcn_mfma_f32_16x16x32_bf16(a[mt], bu[nt], accu[mt][nt], 0, 0, 0);
        }
    }
    __syncthreads();
  }
#pragma unroll
  for (int mt = 0; mt < 4; ++mt)
#pragma unroll
    for (int r = 0; r < 4; ++r) {
      int gr = row0 + wm + mt * 16 + quad * 4 + r;
#pragma unroll
      for (int nt = 0; nt < 4; ++nt) {
        int gc = col0 + wn + nt * 16 + lcol;
        float g = accg[mt][nt][r], u = accu[mt][nt][r];
        float val = (g * u) / (1.0f + __expf(-g));
        act[(size_t)gr * FF + gc] = f2bf(val);
      }
    }
}

// ---------------- Flash attention via 3x-bf16 MFMA (fp32-class precision) ----------------
// 256 thr (4 waves). Block = (b, h, qt). Wave w owns q-rows qt*64+w*16..+15.
// QK^T: A=Q3 regs [hi|lo], B=K2 LDS [hi|lo] key-major; 6 MFMA per 16x16 n-tile.
// Softmax in regs (C-layout rows=quad*4+r). P -> per-wave LDS strip (hi|lo) -> A-frags.
// PV: B=V2 LDS [hi|lo] dim-major (transposed at staging). O stays in C-layout regs.
// K2/V2 rows: 128 shorts, 16-chunk XOR swizzle (<=4-way conflicts). 2 barriers/k-tile.
__global__ __launch_bounds__(256, 3) void attn_kernel(
    const float* __restrict__ q, const float* __restrict__ k,
    const float* __restrict__ v, short* __restrict__ aout3) {
  const int QTMAP[16] = {0, 15, 1, 14, 2, 13, 3, 12, 4, 11, 5, 10, 6, 9, 7, 8};
  const int bh = blockIdx.x & 63;
  const int qt = QTMAP[blockIdx.x >> 6];
  const int b = bh >> 4, h = bh & 15, kvh = h >> 2;
  __shared__ short K2[64 * 128];
  __shared__ short V2[64 * 128];      // transposed: row = dim
  __shared__ short P2[4 * 16 * 136];  // per-wave strips, stride 136
  const int tid = threadIdx.x;
  const int w = tid >> 6, lane = tid & 63;
  const int lcol = lane & 15, quad = lane >> 4;

  // ---- Q fragments in registers (hi/lo of dims quad*8..+7 and 32+quad*8..+7) ----
  const float* qrow = q + (size_t)(b * 1024 + qt * 64 + w * 16 + lcol) * 1024 + h * 64;
  union { short s[8]; bf16x8 v; } qhi0, qhi1, qlo0, qlo1;
  {
    float e0[8], e1[8];
    float4 f0 = *(const float4*)(qrow + quad * 8);
    float4 f1 = *(const float4*)(qrow + quad * 8 + 4);
    float4 f2 = *(const float4*)(qrow + 32 + quad * 8);
    float4 f3 = *(const float4*)(qrow + 32 + quad * 8 + 4);
    e0[0]=f0.x; e0[1]=f0.y; e0[2]=f0.z; e0[3]=f0.w; e0[4]=f1.x; e0[5]=f1.y; e0[6]=f1.z; e0[7]=f1.w;
    e1[0]=f2.x; e1[1]=f2.y; e1[2]=f2.z; e1[3]=f2.w; e1[4]=f3.x; e1[5]=f3.y; e1[6]=f3.z; e1[7]=f3.w;
#pragma unroll
    for (int i = 0; i < 8; ++i) {
      qhi0.s[i] = f2bf(e0[i]); qlo0.s[i] = f2bf(e0[i] - bf2f(qhi0.s[i]));
      qhi1.s[i] = f2bf(e1[i]); qlo1.s[i] = f2bf(e1[i] - bf2f(qhi1.s[i]));
    }
  }
  f32x4 O[4];
#pragma unroll
  for (int i = 0; i < 4; ++i) O[i] = (f32x4){0.f, 0.f, 0.f, 0.f};
  float m_i[4] = {-1e30f, -1e30f, -1e30f, -1e30f};
  float l_i[4] = {0.f, 0.f, 0.f, 0.f};

  const int skey = tid >> 2, sdq = tid & 3;       // K staging: key, dim-quad
  const int sp = tid >> 3, sdg = tid & 7;         // V staging: key-pair, dim-group
  short* p2w = P2 + w * (16 * 136);

  for (int kt = 0; kt <= qt; ++kt) {
    __syncthreads();  // all PV reads of previous tile done
    // ---- stage K2 [key][hi(0..63)|lo(64..127)], chunk-XOR by key&15 ----
    {
      const float* kr = k + (size_t)(b * 1024 + kt * 64 + skey) * 256 + kvh * 64 + sdq * 16;
      float4 f[4];
      f[0] = *(const float4*)(kr); f[1] = *(const float4*)(kr + 4);
      f[2] = *(const float4*)(kr + 8); f[3] = *(const float4*)(kr + 12);
      short* krow = K2 + skey * 128;
#pragma unroll
      for (int c2 = 0; c2 < 2; ++c2) {
        float e[8];
        e[0]=f[2*c2].x; e[1]=f[2*c2].y; e[2]=f[2*c2].z; e[3]=f[2*c2].w;
        e[4]=f[2*c2+1].x; e[5]=f[2*c2+1].y; e[6]=f[2*c2+1].z; e[7]=f[2*c2+1].w;
        union { short s[8]; s16x4 v4[2]; } Hh, Ll;
#pragma unroll
        for (int i = 0; i < 8; ++i) {
          Hh.s[i] = f2bf(e[i]);
          Ll.s[i] = f2bf(e[i] - bf2f(Hh.s[i]));
        }
        int ch = 2 * sdq + c2;
        int hc = (ch ^ (skey & 15)) * 8;
        int lc = ((8 + ch) ^ (skey & 15)) * 8;
        *(s16x4*)&krow[hc] = Hh.v4[0]; *(s16x4*)&krow[hc + 4] = Hh.v4[1];
        *(s16x4*)&krow[lc] = Ll.v4[0]; *(s16x4*)&krow[lc + 4] = Ll.v4[1];
      }
    }
    // ---- stage V2 transposed [dim][hi keys|lo keys], chunk-XOR by dim&15 ----
    {
      const float* vr0 = v + (size_t)(b * 1024 + kt * 64 + 2 * sp) * 256 + kvh * 64 + sdg * 8;
      const float* vr1 = vr0 + 256;
      float4 a0 = *(const float4*)(vr0), a1 = *(const float4*)(vr0 + 4);
      float4 b0 = *(const float4*)(vr1), b1 = *(const float4*)(vr1 + 4);
      float va[8], vb[8];
      va[0]=a0.x; va[1]=a0.y; va[2]=a0.z; va[3]=a0.w; va[4]=a1.x; va[5]=a1.y; va[6]=a1.z; va[7]=a1.w;
      vb[0]=b0.x; vb[1]=b0.y; vb[2]=b0.z; vb[3]=b0.w; vb[4]=b1.x; vb[5]=b1.y; vb[6]=b1.z; vb[7]=b1.w;
      int ch = sp >> 2, di = (sp & 3) * 2;
#pragma unroll
      for (int i = 0; i < 8; ++i) {
        int d = sdg * 8 + i;
        short h0 = f2bf(va[i]), l0 = f2bf(va[i] - bf2f(h0));
        short h1 = f2bf(vb[i]), l1 = f2bf(vb[i] - bf2f(h1));
        uint32_t hp = (uint32_t)(uint16_t)h0 | ((uint32_t)(uint16_t)h1 << 16);
        uint32_t lp = (uint32_t)(uint16_t)l0 | ((uint32_t)(uint16_t)l1 << 16);
        short* vrow = V2 + d * 128;
        *(uint32_t*)&vrow[(ch ^ (d & 15)) * 8 + di] = hp;
        *(uint32_t*)&vrow[((8 + ch) ^ (d & 15)) * 8 + di] = lp;
      }
    }
    __syncthreads();
    // ---- QK^T: 6 MFMA per n-tile ----
    f32x4 S[4];
#pragma unroll
    for (int nt = 0; nt < 4; ++nt) {
      S[nt] = (f32x4){0.f, 0.f, 0.f, 0.f};
      const short* krow = K2 + (nt * 16 + lcol) * 128;
      bf16x8 kh0 = *(const bf16x8*)&krow[(quad ^ lcol) * 8];
      bf16x8 kh1 = *(const bf16x8*)&krow[((4 + quad) ^ lcol) * 8];
      bf16x8 kl0 = *(const bf16x8*)&krow[((8 + quad) ^ lcol) * 8];
      bf16x8 kl1 = *(const bf16x8*)&krow[((12 + quad) ^ lcol) * 8];
      S[nt] = __builtin_amdgcn_mfma_f32_16x16x32_bf16(qhi0.v, kh0, S[nt], 0, 0, 0);
      S[nt] = __builtin_amdgcn_mfma_f32_16x16x32_bf16(qhi1.v, kh1, S[nt], 0, 0, 0);
      S[nt] = __builtin_amdgcn_mfma_f32_16x16x32_bf16(qlo0.v, kh0, S[nt], 0, 0, 0);
      S[nt] = __builtin_amdgcn_mfma_f32_16x16x32_bf16(qlo1.v, kh1, S[nt], 0, 0, 0);
      S[nt] = __builtin_amdgcn_mfma_f32_16x16x32_bf16(qhi0.v, kl0, S[nt], 0, 0, 0);
      S[nt] = __builtin_amdgcn_mfma_f32_16x16x32_bf16(qhi1.v, kl1, S[nt], 0, 0, 0);
    }
    // ---- online softmax (C-layout: row=quad*4+r, col=nt*16+lcol) + P write ----
    const bool diag = (kt == qt);
#pragma unroll
    for (int r = 0; r < 4; ++r) {
      float sv[4];
#pragma unroll
      for (int nt = 0; nt < 4; ++nt) sv[nt] = S[nt][r] * 0.125f;
      if (diag) {
        int rl = w * 16 + quad * 4 + r;  // local row within q-tile
#pragma unroll
        for (int nt = 0; nt < 4; ++nt)
          if (nt * 16 + lcol > rl) sv[nt] = -1e30f;
      }
      float mx = fmaxf(fmaxf(sv[0], sv[1]), fmaxf(sv[2], sv[3]));
      mx = fmaxf(mx, __shfl_xor(mx, 1));
      mx = fmaxf(mx, __shfl_xor(mx, 2));
      mx = fmaxf(mx, __shfl_xor(mx, 4));
      mx = fmaxf(mx, __shfl_xor(mx, 8));
      float m_new = fmaxf(m_i[r], mx);
      float pe[4], rs = 0.f;
#pragma unroll
      for (int nt = 0; nt < 4; ++nt) { pe[nt] = __expf(sv[nt] - m_new); rs += pe[nt]; }
      rs += __shfl_xor(rs, 1);
      rs += __shfl_xor(rs, 2);
      rs += __shfl_xor(rs, 4);
      rs += __shfl_xor(rs, 8);
      float alpha = __expf(m_i[r] - m_new);
      l_i[r] = l_i[r] * alpha + rs;
      m_i[r] = m_new;
      O[0][r] *= alpha; O[1][r] *= alpha; O[2][r] *= alpha; O[3][r] *= alpha;
      short* prow = p2w + (quad * 4 + r) * 136;
#pragma unroll
      for (int nt = 0; nt < 4; ++nt) {
        short hb = f2bf(pe[nt]);
        prow[nt * 16 + lcol] = hb;
        prow[64 + nt * 16 + lcol] = f2bf(pe[nt] - bf2f(hb));
      }
    }
    // ---- PV: own-wave P strip (in-order LDS) + shared V2 ----
    {
      const short* pr = p2w + lcol * 136;
      bf16x8 ph0 = *(const bf16x8*)&pr[quad * 8];
      bf16x8 ph1 = *(const bf16x8*)&pr[32 + quad * 8];
      bf16x8 pl0 = *(const bf16x8*)&pr[64 + quad * 8];
      bf16x8 pl1 = *(const bf16x8*)&pr[96 + quad * 8];
#pragma unroll
      for (int nt = 0; nt < 4; ++nt) {
        const short* vrow = V2 + (nt * 16 + lcol) * 128;
        bf16x8 vh0 = *(const bf16x8*)&vrow[(quad ^ lcol) * 8];
        bf16x8 vh1 = *(const bf16x8*)&vrow[((4 + quad) ^ lcol) * 8];
        bf16x8 vl0 = *(const bf16x8*)&vrow[((8 + quad) ^ lcol) * 8];
        bf16x8 vl1 = *(const bf16x8*)&vrow[((12 + quad) ^ lcol) * 8];
        O[nt] = __builtin_amdgcn_mfma_f32_16x16x32_bf16(ph0, vh0, O[nt], 0, 0, 0);
        O[nt] = __builtin_amdgcn_mfma_f32_16x16x32_bf16(ph1, vh1, O[nt], 0, 0, 0);
        O[nt] = __builtin_amdgcn_mfma_f32_16x16x32_bf16(pl0, vh0, O[nt], 0, 0, 0);
        O[nt] = __builtin_amdgcn_mfma_f32_16x16x32_bf16(pl1, vh1, O[nt], 0, 0, 0);
        O[nt] = __builtin_amdgcn_mfma_f32_16x16x32_bf16(ph0, vl0, O[nt], 0, 0, 0);
        O[nt] = __builtin_amdgcn_mfma_f32_16x16x32_bf16(ph1, vl1, O[nt], 0, 0, 0);
      }
    }
  }
  // ---- epilogue: normalize, 3x-bf16 out ----
#pragma unroll
  for (int r = 0; r < 4; ++r) {
    float inv = 1.0f / l_i[r];
    size_t tok = (size_t)(b * 1024 + qt * 64 + w * 16 + quad * 4 + r);
#pragma unroll
    for (int nt = 0; nt < 4; ++nt) {
      float val = O[nt][r] * inv;
      short hb = f2bf(val);
      short lb = f2bf(val - bf2f(hb));
      size_t tb = tok * 3072 + h * 64 + nt * 16 + lcol;
      aout3[tb] = hb;
      aout3[tb + 1024] = lb;
      aout3[tb + 2048] = hb;
    }
  }
}

// ---------------- Router ----------------
__global__ __launch_bounds__(64) void gate_topk(
    const float* __restrict__ hn, const float* __restrict__ Wgate,
    float* __restrict__ topk_p, int* __restrict__ topk_i, int* __restrict__ counts) {
  int t = blockIdx.x, lane = threadIdx.x;
  float acc[8] = {};
  for (int i = lane; i < 1024; i += 64) {
    float xv = hn[(size_t)t * 1024 + i];
    const float4 w0 = *(const float4*)(Wgate + i * 8);
    const float4 w1 = *(const float4*)(Wgate + i * 8 + 4);
    acc[0] += xv * w0.x; acc[1] += xv * w0.y; acc[2] += xv * w0.z; acc[3] += xv * w0.w;
    acc[4] += xv * w1.x; acc[5] += xv * w1.y; acc[6] += xv * w1.z; acc[7] += xv * w1.w;
  }
#pragma unroll
  for (int e = 0; e < 8; ++e)
#pragma unroll
    for (int off = 32; off > 0; off >>= 1) acc[e] += __shfl_down(acc[e], off);
  if (lane == 0) {
    float m = acc[0];
#pragma unroll
    for (int e = 1; e < 8; ++e) m = fmaxf(m, acc[e]);
    float p[8], s = 0.0f;
#pragma unroll
    for (int e = 0; e < 8; ++e) { p[e] = __expf(acc[e] - m); s += p[e]; }
    float invs = 1.0f / s;
#pragma unroll
    for (int e = 0; e < 8; ++e) p[e] *= invs;
    int i1 = 0;
#pragma unroll
    for (int e = 1; e < 8; ++e) if (p[e] > p[i1]) i1 = e;
    int i2 = (i1 == 0) ? 1 : 0;
#pragma unroll
    for (int e = 0; e < 8; ++e) if (e != i1 && p[e] > p[i2]) i2 = e;
    topk_i[t * 2] = i1;     topk_p[t * 2] = p[i1];
    topk_i[t * 2 + 1] = i2; topk_p[t * 2 + 1] = p[i2];
    atomicAdd(&counts[i1], 1);
    atomicAdd(&counts[i2], 1);
  }
}

__global__ void moe_init(int* __restrict__ pair_token, int* __restrict__ counts) {
  int i = blockIdx.x * 256 + threadIdx.x;
  if (i < MAXROWS) pair_token[i] = -1;
  if (i < NEXP) counts[i] = 0;
}

__global__ void moe_prefix(const int* __restrict__ counts, int* __restrict__ seg_off,
                           int* __restrict__ cursor, int* __restrict__ tile_expert) {
  if (threadIdx.x == 0 && blockIdx.x == 0) {
    int so[9];
    int off = 0;
    for (int e = 0; e < 8; ++e) {
      so[e] = off; seg_off[e] = off; cursor[e] = 0;
      off += (counts[e] + 127) & ~127;
    }
    so[8] = off; seg_off[8] = off;
    for (int i = 0; i < MAXT128; ++i) {
      int row = i * 128, e = -1;
      for (int x = 0; x < 8; ++x)
        if (row >= so[x] && row < so[x + 1]) e = x;
      tile_expert[i] = e;
    }
  }
}

__global__ void moe_scatter(const int* __restrict__ topk_i, const int* __restrict__ seg_off,
                            int* __restrict__ cursor, int* __restrict__ pair_token,
                            int* __restrict__ slot_idx) {
  int idx = blockIdx.x * 256 + threadIdx.x;
  if (idx >= T_TOK * 2) return;
  int e = topk_i[idx];
  int slot = seg_off[e] + atomicAdd(&cursor[e], 1);
  pair_token[slot] = idx >> 1;
  slot_idx[idx] = slot;
}

// ---------------- Gather routed rows to dense bf16 ----------------
__global__ __launch_bounds__(128) void gather_rows(
    const float* __restrict__ hn, const int* __restrict__ pair_token,
    short* __restrict__ xg) {
  int slot = blockIdx.x, t = threadIdx.x;
  int tok = pair_token[slot];
  union { short s[8]; bf16x8 v; } P;
  if (tok >= 0) {
    const float4 a = *(const float4*)(hn + (size_t)tok * 1024 + t * 8);
    const float4 bb = *(const float4*)(hn + (size_t)tok * 1024 + t * 8 + 4);
    P.s[0] = f2bf(a.x); P.s[1] = f2bf(a.y); P.s[2] = f2bf(a.z); P.s[3] = f2bf(a.w);
    P.s[4] = f2bf(bb.x); P.s[5] = f2bf(bb.y); P.s[6] = f2bf(bb.z); P.s[7] = f2bf(bb.w);
  } else {
#pragma unroll
    for (int i = 0; i < 8; ++i) P.s[i] = 0;
  }
  *(bf16x8*)(xg + (size_t)slot * 1024 + t * 8) = P.v;
}

// ---------------- Final combine ----------------
__global__ __launch_bounds__(256) void final_combine(
    const float* __restrict__ hbuf, const float* __restrict__ pair_out,
    const int* __restrict__ slot_idx, const float* __restrict__ topk_p,
    float* __restrict__ out) {
  int t = blockIdx.x, d = threadIdx.x;
  int s0 = slot_idx[t * 2], s1 = slot_idx[t * 2 + 1];
  float p0 = topk_p[t * 2], p1 = topk_p[t * 2 + 1];
  float4 hv = *(const float4*)(hbuf + (size_t)t * 1024 + d * 4);
  float4 a = *(const float4*)(pair_out + (size_t)s0 * 1024 + d * 4);
  float4 b = *(const float4*)(pair_out + (size_t)s1 * 1024 + d * 4);
  float4 o;
  o.x = hv.x + p0 * a.x + p1 * b.x;
  o.y = hv.y + p0 * a.y + p1 * b.y;
  o.z = hv.z + p0 * a.z + p1 * b.z;
  o.w = hv.w + p0 * a.w + p1 * b.w;
  *(float4*)(out + (size_t)t * 1024 + d * 4) = o;
}

extern "C" void kernel_launch(void* const* d_in, const int* in_sizes, int n_in,
                              void* d_out, int out_size, void* d_ws, size_t ws_size,
                              hipStream_t stream) {
  const float* x     = (const float*)d_in[0];
  const float* w_ln1 = (const float*)d_in[2];
  const float* w_ln2 = (const float*)d_in[3];
  const float* Wq    = (const float*)d_in[4];
  const float* Wk    = (const float*)d_in[5];
  const float* Wv    = (const float*)d_in[6];
  const float* Wo    = (const float*)d_in[7];
  const float* Wgate = (const float*)d_in[8];
  const float* Wg    = (const float*)d_in[9];
  const float* Wu    = (const float*)d_in[10];
  const float* Wd    = (const float*)d_in[11];
  float* out = (float*)d_out;

  char* base = (char*)d_ws;
  const size_t SZ_XN3  = (size_t)T_TOK * 3072 * 2;   // 25,165,824
  const size_t SZ_WQ3  = (size_t)1024 * 3072 * 2;    //  6,291,456
  const size_t SZ_WKV3 = (size_t)256 * 3072 * 2;     //  1,572,864
  const size_t SZ_Q    = (size_t)T_TOK * 1024 * 4;   // 16,777,216
  short* xn3  = (short*)base;
  short* Wq3t = (short*)(base + SZ_XN3);
  short* Wk3t = (short*)(base + SZ_XN3 + SZ_WQ3);
  short* Wv3t = (short*)(base + SZ_XN3 + SZ_WQ3 + SZ_WKV3);
  float* qbuf = (float*)(base + SZ_XN3 + SZ_WQ3 + 2 * SZ_WKV3);
  float* pair_out = (float*)base;  // alias region A
  size_t offB = SZ_XN3 + SZ_WQ3 + 2 * SZ_WKV3 + SZ_Q;
  const size_t SZ_KV  = (size_t)T_TOK * 256 * 4;     //  4,194,304
  float* kbuf  = (float*)(base + offB);
  float* vbuf  = (float*)(base + offB + SZ_KV);
  short* aout3 = (short*)(base + offB + 2 * SZ_KV);
  short* Wo3t  = (short*)(base + offB + 2 * SZ_KV + SZ_XN3);
  short* act   = (short*)(base + offB);  // alias region B
  size_t off2 = offB + 2 * SZ_KV + SZ_XN3 + SZ_WQ3;
  float* hbuf = (float*)(base + off2);                 off2 += (size_t)T_TOK * 1024 * 4;
  float* hn   = (float*)(base + off2);                 off2 += (size_t)T_TOK * 1024 * 4;
  short* xg   = (short*)(base + off2);                 off2 += (size_t)MAXROWS * 1024 * 2;
  short* Wg_t = (short*)(base + off2);                 off2 += (size_t)NEXP * H_DIM * FF * 2;
  short* Wu_t = (short*)(base + off2);                 off2 += (size_t)NEXP * H_DIM * FF * 2;
  short* Wd_t = (short*)(base + off2);                 off2 += (size_t)NEXP * H_DIM * FF * 2;
  float* topk_p = (float*)(base + off2);               off2 += (size_t)T_TOK * 2 * 4;
  int* topk_i      = (int*)(base + off2);              off2 += (size_t)T_TOK * 2 * 4;
  int* slot_idx    = (int*)(base + off2);              off2 += (size_t)T_TOK * 2 * 4;
  int* pair_token  = (int*)(base + off2);              off2 += (size_t)MAXROWS * 4;
  int* counts      = (int*)(base + off2);              off2 += 64;
  int* cursor      = (int*)(base + off2);              off2 += 64;
  int* seg_off     = (int*)(base + off2);              off2 += 64;
  int* tile_expert = (int*)(base + off2);              off2 += 512;

  conv_t3<<<dim3(32, 32), 256, 0, stream>>>(Wq, Wq3t, 1024, 1024);
  conv_t3<<<dim3(8, 32), 256, 0, stream>>>(Wk, Wk3t, 1024, 256);
  conv_t3<<<dim3(8, 32), 256, 0, stream>>>(Wv, Wv3t, 1024, 256);
  conv_t3<<<dim3(32, 32), 256, 0, stream>>>(Wo, Wo3t, 1024, 1024);
  conv_t1<<<dim3(64, 32, 8), 256, 0, stream>>>(Wg, Wg_t, 1024, 2048);
  conv_t1<<<dim3(64, 32, 8), 256, 0, stream>>>(Wu, Wu_t, 1024, 2048);
  conv_t1<<<dim3(32, 64, 8), 256, 0, stream>>>(Wd, Wd_t, 2048, 1024);

  rmsnorm3_kernel<<<T_TOK, 256, 0, stream>>>(x, w_ln1, nullptr, xn3);
  gemm_bf16<<<dim3(8, 32), 256, 0, stream>>>(xn3, Wq3t, nullptr, qbuf, 1024, 3072, nullptr, 0);
  gemm_bf16<<<dim3(2, 32), 256, 0, stream>>>(xn3, Wk3t, nullptr, kbuf, 256, 3072, nullptr, 0);
  gemm_bf16<<<dim3(2, 32), 256, 0, stream>>>(xn3, Wv3t, nullptr, vbuf, 256, 3072, nullptr, 0);
  attn_kernel<<<dim3(1024), 256, 0, stream>>>(qbuf, kbuf, vbuf, aout3);
  gemm_bf16<<<dim3(8, 32), 256, 0, stream>>>(aout3, Wo3t, x, hbuf, 1024, 3072, nullptr, 0);
  rmsnorm3_kernel<<<T_TOK, 256, 0, stream>>>(hbuf, w_ln2, hn, nullptr);
  moe_init<<<(MAXROWS + 255) / 256, 256, 0, stream>>>(pair_token, counts);
  gate_topk<<<T_TOK, 64, 0, stream>>>(hn, Wgate, topk_p, topk_i, counts);
  moe_prefix<<<1, 64, 0, stream>>>(counts, seg_off, cursor, tile_expert);
  moe_scatter<<<(T_TOK * 2 + 255) / 256, 256, 0, stream>>>(topk_i, seg_off, cursor,
                                                           pair_token, slot_idx);
  gather_rows<<<MAXROWS, 128, 0, stream>>>(hn, pair_token, xg);
  moe_gemm1_bf16<<<dim3(16, MAXT128), 256, 0, stream>>>(xg, Wg_t, Wu_t, tile_expert, act);
  gemm_bf16<<<dim3(8, MAXT128), 256, 0, stream>>>(act, Wd_t, nullptr, pair_out, 1024, 2048,
                                                  tile_expert, (long long)FF * H_DIM);
  final_combine<<<T_TOK, 256, 0, stream>>>(hbuf, pair_out, slot_idx, topk_p, out);
}